// Round 10
// baseline (950.400 us; speedup 1.0000x reference)
//
#include <hip/hip_runtime.h>
#include <math.h>

#define EPS_C 0.001f
#define BATCH 16384

// ---------------- H = X^T X + eps*I  (1152x1152), symmetric: compute bi<=bj, mirror ----------------
__global__ __launch_bounds__(256) void k_xtx(const float* __restrict__ X, float* __restrict__ H) {
  __shared__ float smem[64 * 65];
  const int bi64 = blockIdx.x, bj64 = blockIdx.y;
  if (bi64 > bj64) return;
  float (*sA)[65] = (float(*)[65])smem;
  float (*sB)[65] = (float(*)[65])(smem + 32 * 65);
  const int t = threadIdx.x;
  const int bi = bi64 * 64, bj = bj64 * 64;
  const int tj = t & 15, ti = t >> 4;
  float acc[4][4] = {};
  for (int k0 = 0; k0 < 1152; k0 += 32) {
    #pragma unroll
    for (int l = 0; l < 2; ++l) {
      int idx = t + l * 256;
      int kk = idx >> 4, c4 = (idx & 15) << 2;
      float4 va = *(const float4*)&X[(k0 + kk) * 1152 + bi + c4];
      sA[kk][c4 + 0] = va.x; sA[kk][c4 + 1] = va.y; sA[kk][c4 + 2] = va.z; sA[kk][c4 + 3] = va.w;
      float4 vb = *(const float4*)&X[(k0 + kk) * 1152 + bj + c4];
      sB[kk][c4 + 0] = vb.x; sB[kk][c4 + 1] = vb.y; sB[kk][c4 + 2] = vb.z; sB[kk][c4 + 3] = vb.w;
    }
    __syncthreads();
    #pragma unroll
    for (int kk = 0; kk < 32; ++kk) {
      float am[4], bn[4];
      #pragma unroll
      for (int q = 0; q < 4; ++q) am[q] = sA[kk][ti * 4 + q];
      #pragma unroll
      for (int q = 0; q < 4; ++q) bn[q] = sB[kk][tj * 4 + q];
      #pragma unroll
      for (int r = 0; r < 4; ++r)
        #pragma unroll
        for (int c = 0; c < 4; ++c)
          acc[r][c] = fmaf(am[r], bn[c], acc[r][c]);
    }
    __syncthreads();
  }
  #pragma unroll
  for (int r = 0; r < 4; ++r) {
    int gi = bi + ti * 4 + r;
    float vv[4];
    #pragma unroll
    for (int c = 0; c < 4; ++c) {
      vv[c] = acc[r][c];
      if (gi == bj + tj * 4 + c) vv[c] += EPS_C;
    }
    float4 o = make_float4(vv[0], vv[1], vv[2], vv[3]);
    *(float4*)&H[gi * 1152 + bj + tj * 4] = o;
  }
  if (bi64 < bj64) {
    float (*tr)[65] = (float(*)[65])smem;
    #pragma unroll
    for (int r = 0; r < 4; ++r)
      #pragma unroll
      for (int c = 0; c < 4; ++c)
        tr[tj * 4 + c][ti * 4 + r] = acc[r][c];
    __syncthreads();
    #pragma unroll
    for (int l = 0; l < 4; ++l) {
      int e = t + l * 256;
      int row = e >> 4, c4 = (e & 15) << 2;
      float4 o = make_float4(tr[row][c4], tr[row][c4 + 1], tr[row][c4 + 2], tr[row][c4 + 3]);
      *(float4*)&H[(bj + row) * 1152 + bi + c4] = o;
    }
  }
}

// ---------------- assemble M=[E^T | C2^T], D11, Lam, xc, Fx ----------------
__global__ __launch_bounds__(256) void k_assemble(const float* __restrict__ H, const float* __restrict__ Y,
                           const float* __restrict__ C2, const float* __restrict__ x0,
                           float* __restrict__ M, float* __restrict__ D11,
                           float* __restrict__ Lam, float* __restrict__ xc, float* __restrict__ Fx) {
  const int b = blockIdx.x;
  const int t = threadIdx.x;
  if (b < 256) {
    __shared__ float tA[32][33], tB[32][33], tC[32][33];
    const int R0 = (b & 15) * 32, C0 = (b >> 4) * 32;
    const int c = t & 31, rr = t >> 5;
    #pragma unroll
    for (int p = 0; p < 4; ++p) {
      int row = rr + p * 8;
      tA[row][c] = H[(C0 + row) * 1152 + R0 + c];
      tB[row][c] = H[(640 + C0 + row) * 1152 + 640 + R0 + c];
      tC[row][c] = Y[(C0 + row) * 512 + R0 + c];
    }
    __syncthreads();
    #pragma unroll
    for (int p = 0; p < 4; ++p) {
      int r = rr + p * 8;
      float val = 0.5f * (tA[c][r] + tB[c][r] + tC[c][r] - Y[(R0 + r) * 512 + C0 + c]);
      M[(R0 + r) * 640 + C0 + c] = val;
    }
  } else if (b < 320) {
    int e0 = (b - 256) * 1024;
    #pragma unroll
    for (int l = 0; l < 4; ++l) {
      int e = e0 + l * 256 + t;
      int r = e >> 7, o = e & 127;
      M[r * 640 + 512 + o] = C2[o * 512 + r];
    }
  } else if (b < 384) {
    int e = (b - 320) * 256 + t;
    int i = e >> 7, j = e & 127;
    D11[e] = (j < i) ? -H[(512 + i) * 1152 + 512 + j] : 0.0f;
  } else if (b == 384) {
    if (t < 128) Lam[t] = 0.5f * H[(512 + t) * 1152 + 512 + t];
  } else if (b == 385) {
    if (t < 128) {
      float s = 0.f;
      for (int a = 0; a < 512; ++a) s = fmaf(H[(512 + t) * 1152 + a], x0[a], s);
      xc[t] = -s;
    }
  } else {
    int r = (b - 386) * 256 + t;
    float s = 0.f;
    for (int a = 0; a < 512; ++a) s = fmaf(H[(640 + r) * 1152 + a], x0[a], s);
    Fx[r] = s;
  }
}

// ---------------- fused diag+panels: every block redundantly factors the 64x64 diag in registers
//                  (no inter-block sync); block 0 persists factored diag to Dfac (NOT in-place: race-free) ----------------
__global__ __launch_bounds__(64) void k_lu_dp(float* __restrict__ M, float* __restrict__ Dfac, int kb) {
  __shared__ float sD[64 * 65];
  __shared__ float sRD[64];
  const int t = threadIdx.x;
  const int nU = 9 - kb;
  const int pb = blockIdx.x;
  // issue panel loads early (panel strips are untouched by the diag factor)
  float v[64];
  int c = 0, rr = 0;
  if (pb < nU) {
    c = 64 * (kb + 1) + pb * 64 + t;
    #pragma unroll
    for (int i = 0; i < 64; ++i) v[i] = M[(kb * 64 + i) * 640 + c];
  } else {
    rr = 64 * (kb + 1) + (pb - nU) * 64 + t;
    #pragma unroll
    for (int i = 0; i < 16; ++i) *(float4*)&v[i * 4] = *(const float4*)&M[rr * 640 + kb * 64 + i * 4];
  }
  // redundant in-register LU factor of diag (reads ORIGINAL M diag; M's diag is never overwritten)
  {
    const float* blk = M + kb * 64 * 640 + kb * 64;
    float col[64];
    #pragma unroll
    for (int r = 0; r < 64; ++r) col[r] = blk[r * 640 + t];
    float invp = 1.0f;
    #pragma unroll
    for (int k = 0; k < 64; ++k) {
      float piv = __shfl(col[k], k);
      float inv = 1.0f / piv;
      if (t == k) invp = inv;
      float m = col[k] * inv;
      bool act = t > k;
      #pragma unroll
      for (int r = k + 1; r < 64; ++r) {
        float ckr = __shfl(col[r], k);
        if (act) col[r] -= ckr * m;
      }
    }
    #pragma unroll
    for (int r = 0; r < 64; ++r) {
      if (r > t) col[r] *= invp;
      sD[r * 65 + t] = col[r];
      if (pb == 0) Dfac[kb * 4096 + r * 64 + t] = col[r];
    }
    sRD[t] = invp;  // == 1/sD[t*65+t] bitwise
  }
  __syncthreads();
  if (pb < nU) {
    #pragma unroll
    for (int i = 1; i < 64; ++i) {
      float a0 = v[i], a1 = 0.f;
      #pragma unroll
      for (int j = 0; j < i; j += 2) {
        a0 = fmaf(-sD[i * 65 + j], v[j], a0);
        if (j + 1 < i) a1 = fmaf(-sD[i * 65 + j + 1], v[j + 1], a1);
      }
      v[i] = a0 + a1;
    }
    #pragma unroll
    for (int i = 0; i < 64; ++i) M[(kb * 64 + i) * 640 + c] = v[i];
  } else {
    #pragma unroll
    for (int j = 0; j < 64; ++j) {
      float a0 = v[j], a1 = 0.f;
      #pragma unroll
      for (int i = 0; i < j; i += 2) {
        a0 = fmaf(-v[i], sD[i * 65 + j], a0);
        if (i + 1 < j) a1 = fmaf(-v[i + 1], sD[(i + 1) * 65 + j], a1);
      }
      v[j] = (a0 + a1) * sRD[j];
    }
    #pragma unroll
    for (int i = 0; i < 16; ++i) *(float4*)&M[rr * 640 + kb * 64 + i * 4] = *(float4*)&v[i * 4];
  }
}

// ---------------- trailing update: A22 -= L21 * U12 (cols include augmented) ----------------
__global__ __launch_bounds__(256) void k_lu_trailing(float* __restrict__ M, int kb) {
  __shared__ float sL[32][65];
  __shared__ float sU[32][65];
  const int t = threadIdx.x;
  const int base = 64 * (kb + 1);
  const int r0 = base + blockIdx.y * 64, c0 = base + blockIdx.x * 64;
  const int tj = t & 15, ti = t >> 4;
  float acc[4][4] = {};
  for (int k0 = 0; k0 < 64; k0 += 32) {
    #pragma unroll
    for (int l = 0; l < 2; ++l) {
      int idx = t + l * 256;
      int row = idx >> 3, k4 = (idx & 7) << 2;
      float4 v = *(const float4*)&M[(r0 + row) * 640 + kb * 64 + k0 + k4];
      sL[k4 + 0][row] = v.x; sL[k4 + 1][row] = v.y; sL[k4 + 2][row] = v.z; sL[k4 + 3][row] = v.w;
      int kk = idx >> 4, c4 = (idx & 15) << 2;
      float4 u4 = *(const float4*)&M[(kb * 64 + k0 + kk) * 640 + c0 + c4];
      sU[kk][c4 + 0] = u4.x; sU[kk][c4 + 1] = u4.y; sU[kk][c4 + 2] = u4.z; sU[kk][c4 + 3] = u4.w;
    }
    __syncthreads();
    #pragma unroll
    for (int kk = 0; kk < 32; ++kk) {
      float am[4], bn[4];
      #pragma unroll
      for (int q = 0; q < 4; ++q) am[q] = sL[kk][ti * 4 + q];
      #pragma unroll
      for (int q = 0; q < 4; ++q) bn[q] = sU[kk][tj * 4 + q];
      #pragma unroll
      for (int r = 0; r < 4; ++r)
        #pragma unroll
        for (int c = 0; c < 4; ++c)
          acc[r][c] = fmaf(am[r], bn[c], acc[r][c]);
    }
    __syncthreads();
  }
  #pragma unroll
  for (int r = 0; r < 4; ++r) {
    float4 old = *(float4*)&M[(r0 + ti * 4 + r) * 640 + c0 + tj * 4];
    old.x -= acc[r][0]; old.y -= acc[r][1]; old.z -= acc[r][2]; old.w -= acc[r][3];
    *(float4*)&M[(r0 + ti * 4 + r) * 640 + c0 + tj * 4] = old;
  }
}

// ---------------- invert each factored 64x64 diag block: invU[kb] = U_kk^-1 (8 parallel blocks) ----------------
__global__ __launch_bounds__(64) void k_inv(const float* __restrict__ Dfac, float* __restrict__ invU) {
  __shared__ float sD[64 * 65];
  __shared__ float srs[64];
  const int t = threadIdx.x;
  const int kb = blockIdx.x;
  for (int l = 0; l < 64; ++l) sD[l * 65 + t] = Dfac[kb * 4096 + l * 64 + t];
  __syncthreads();
  srs[t] = 1.0f / sD[t * 65 + t];
  __syncthreads();
  // column t of U^-1 via back-substitution, fully unrolled, registers only
  float v[64];
  #pragma unroll
  for (int i = 0; i < 64; ++i) v[i] = (i == t) ? srs[t] : 0.0f;
  #pragma unroll
  for (int i = 62; i >= 0; --i) {
    float a0 = 0.f, a1 = 0.f;
    #pragma unroll
    for (int j = i + 1; j < 64; j += 2) {
      a0 = fmaf(-sD[i * 65 + j], v[j], a0);
      if (j + 1 < 64) a1 = fmaf(-sD[i * 65 + j + 1], v[j + 1], a1);
    }
    float nv = (a0 + a1) * srs[i];
    v[i] = (i == t) ? v[i] : nv;   // nv==0 naturally for i>t (strictly-upper zeros)
  }
  #pragma unroll
  for (int i = 0; i < 64; ++i) invU[kb * 4096 + i * 64 + t] = v[i];
}

// ---------------- backward solve U * Gt = Z : 8 INDEPENDENT column-slice blocks (16 cols each) ----------------
__global__ __launch_bounds__(512, 2) void k_bs(const float* __restrict__ M, const float* __restrict__ invUg,
                                               float* __restrict__ Gt) {
  __shared__ float sZ[512 * 17];     // 512 rows x 16 cols, stride 17 (bank-spread)
  __shared__ float sU[64 * 65];
  __shared__ float sI[64 * 65];      // padded: (i*65+k)%32 varies with i
  const int t = threadIdx.x;
  const int c0 = blockIdx.x * 16;
  const int o = t & 15, q = t >> 4;  // q in [0,32): row-thread groups
  // load this block's Z slice (augmented columns of M)
  #pragma unroll
  for (int l = 0; l < 16; ++l) {
    int e = t + l * 512;
    int r = e >> 4, oo = e & 15;
    sZ[r * 17 + oo] = M[r * 640 + 512 + c0 + oo];
  }
  for (int kb = 7; kb >= 0; --kb) {
    // stage invU(kb), padded stride
    #pragma unroll
    for (int l = 0; l < 8; ++l) {
      int e = t + l * 512;
      int r = e >> 6, k = e & 63;
      sI[r * 65 + k] = invUg[kb * 4096 + r * 64 + k];
    }
    __syncthreads();   // covers initial sZ load (first iter) + sI staging + prior updates
    // x_kb = invU @ z_kb : read phase
    float xv[2];
    #pragma unroll
    for (int rr = 0; rr < 2; ++rr) {
      int i = q * 2 + rr;
      float a0 = 0.f, a1 = 0.f;
      #pragma unroll
      for (int k = 0; k < 64; k += 2) {
        a0 = fmaf(sI[i * 65 + k], sZ[(kb * 64 + k) * 17 + o], a0);
        a1 = fmaf(sI[i * 65 + k + 1], sZ[(kb * 64 + k + 1) * 17 + o], a1);
      }
      xv[rr] = a0 + a1;
    }
    __syncthreads();   // all reads of z_kb done before overwrite
    #pragma unroll
    for (int rr = 0; rr < 2; ++rr) {
      int i = q * 2 + rr;
      sZ[(kb * 64 + i) * 17 + o] = xv[rr];
      Gt[(kb * 64 + i) * 128 + c0 + o] = xv[rr];
    }
    __syncthreads();
    if (kb == 0) break;
    // hoist x_kb into registers once (each thread: its own column o) -- STATIC indices only
    float xk[64];
    #pragma unroll
    for (int k = 0; k < 64; ++k) xk[k] = sZ[(kb * 64 + k) * 17 + o];
    // updates: z_i -= U(i,kb) @ x_kb for i < kb, with reg-staged double-buffered U tiles
    float bufA[8], bufB[8];
    #pragma unroll
    for (int l = 0; l < 8; ++l) {
      int e = t + l * 512;
      int r = e >> 6, k = e & 63;
      bufA[l] = M[r * 640 + kb * 64 + k];          // i = 0 tile
    }
    for (int i = 0; i < kb; ++i) {
      #pragma unroll
      for (int l = 0; l < 8; ++l) {
        int e = t + l * 512;
        int r = e >> 6, k = e & 63;
        sU[r * 65 + k] = bufA[l];
      }
      if (i + 1 < kb) {
        #pragma unroll
        for (int l = 0; l < 8; ++l) {
          int e = t + l * 512;
          int r = e >> 6, k = e & 63;
          bufB[l] = M[((i + 1) * 64 + r) * 640 + kb * 64 + k];   // prefetch next tile
        }
      }
      __syncthreads();
      #pragma unroll
      for (int rr = 0; rr < 2; ++rr) {
        int row = q * 2 + rr;
        float acc = sZ[(i * 64 + row) * 17 + o];
        #pragma unroll
        for (int k = 0; k < 64; ++k)
          acc = fmaf(-sU[row * 65 + k], xk[k], acc);
        sZ[(i * 64 + row) * 17 + o] = acc;
      }
      #pragma unroll
      for (int l = 0; l < 8; ++l) bufA[l] = bufB[l];
      __syncthreads();   // compute done reading sU before next iteration overwrites it
    }
  }
}

// ---------------- W1 = G@B1 + D21, W2 = G@B2 + D22, bias = G@Fx ----------------
__global__ void k_wass(const float* __restrict__ Gt, const float* __restrict__ H,
                       const float* __restrict__ B2, const float* __restrict__ D21,
                       const float* __restrict__ D22, const float* __restrict__ Fx,
                       float* __restrict__ W1, float* __restrict__ W2, float* __restrict__ bias) {
  int idx = blockIdx.x * 256 + threadIdx.x;
  if (idx < 16384) {
    int o = idx >> 7, j = idx & 127;
    float s = 0.f;
    for (int a = 0; a < 512; ++a) s = fmaf(Gt[a * 128 + o], H[(640 + a) * 1152 + 512 + j], s);
    W1[idx] = s + D21[idx];
  } else if (idx < 32768) {
    int q = idx - 16384;
    int o = q >> 7, j = q & 127;
    float s = 0.f;
    for (int a = 0; a < 512; ++a) s = fmaf(Gt[a * 128 + o], B2[a * 128 + j], s);
    W2[q] = s + D22[q];
  } else if (idx < 32768 + 128) {
    int o = idx - 32768;
    float s = 0.f;
    for (int a = 0; a < 512; ++a) s = fmaf(Gt[a * 128 + o], Fx[a], s);
    bias[o] = s;
  }
}

// ---------------- baseT[i][b] = xc[i] + (u @ D12^T)[b][i] ----------------
__global__ __launch_bounds__(256) void k_ud(const float* __restrict__ u, const float* __restrict__ D12,
                                            const float* __restrict__ xc, float* __restrict__ baseT) {
  __shared__ float sU[32][65];
  __shared__ float sD[32][65];
  const int t = threadIdx.x;
  const int b0 = blockIdx.x * 64, i0 = blockIdx.y * 64;
  const int tm = t & 15, tn = t >> 4;
  float acc[4][4] = {};
  for (int k0 = 0; k0 < 128; k0 += 32) {
    #pragma unroll
    for (int l = 0; l < 2; ++l) {
      int idx = t + l * 256;
      int row = idx >> 3, k4 = (idx & 7) << 2;
      float4 v = *(const float4*)&u[(b0 + row) * 128 + k0 + k4];
      sU[k4 + 0][row] = v.x; sU[k4 + 1][row] = v.y; sU[k4 + 2][row] = v.z; sU[k4 + 3][row] = v.w;
      float4 d = *(const float4*)&D12[(i0 + row) * 128 + k0 + k4];
      sD[k4 + 0][row] = d.x; sD[k4 + 1][row] = d.y; sD[k4 + 2][row] = d.z; sD[k4 + 3][row] = d.w;
    }
    __syncthreads();
    #pragma unroll
    for (int kk = 0; kk < 32; ++kk) {
      float mm[4], nn[4];
      #pragma unroll
      for (int q = 0; q < 4; ++q) mm[q] = sU[kk][tm * 4 + q];
      #pragma unroll
      for (int q = 0; q < 4; ++q) nn[q] = sD[kk][tn * 4 + q];
      #pragma unroll
      for (int c = 0; c < 4; ++c)
        #pragma unroll
        for (int r = 0; r < 4; ++r)
          acc[c][r] = fmaf(nn[c], mm[r], acc[c][r]);
    }
    __syncthreads();
  }
  #pragma unroll
  for (int c = 0; c < 4; ++c) {
    int i = i0 + tn * 4 + c;
    float xcv = xc[i];
    float4 v = make_float4(acc[c][0] + xcv, acc[c][1] + xcv, acc[c][2] + xcv, acc[c][3] + xcv);
    *(float4*)&baseT[i * BATCH + b0 + tm * 4] = v;
  }
}

// ---------------- scan: w[i] = tanh((base_i + sum_{j<i} D11[i][j] w[j]) / Lam[i]) ----------------
// w-history in LDS (float4-grouped: wl[g*260 + t*4 + e] holds w[4g+e] for this thread's column),
// current 16-step chunk in statically-indexed wc[16] registers, baseT prefetched 16-at-a-time.
// Per-thread LDS columns are private -> no barriers. Term order & 4-acc split identical to the
// original (history j<C by j%4 ascending via ds_read_b128; in-chunk groups while lg+4<=li;
// remainder -> acc0) -> bitwise-identical results. Round-9 evidence: w[128] in "registers" spills
// (VGPR=72, 1 wave/SIMD, nothing hides scratch); this caps live registers at ~50.
__global__ __launch_bounds__(64) void k_scan(const float* __restrict__ baseT, const float* __restrict__ D11g,
                                             const float* __restrict__ Lam, float* __restrict__ wT) {
  __shared__ float wl[32 * 260];   // 32 groups x (64 threads x 4 elems + 4 pad)
  const int t = threadIdx.x;
  const int b = blockIdx.x * 64 + t;
  for (int c = 0; c < 8; ++c) {
    const int C = c * 16;
    float bt[16];
    #pragma unroll
    for (int l = 0; l < 16; ++l) bt[l] = baseT[(C + l) * BATCH + b];
    float wc[16];
    #pragma unroll
    for (int li = 0; li < 16; ++li) {
      const int i = C + li;
      float acc0 = bt[li], acc1 = 0.f, acc2 = 0.f, acc3 = 0.f;
      const float* __restrict__ Drow = D11g + i * 128;
      // history: j < C, one ds_read_b128 per 4 ascending-j terms
      for (int g = 0; g < C / 4; ++g) {
        float4 wv = *(const float4*)&wl[g * 260 + t * 4];
        acc0 = fmaf(wv.x, Drow[g * 4 + 0], acc0);
        acc1 = fmaf(wv.y, Drow[g * 4 + 1], acc1);
        acc2 = fmaf(wv.z, Drow[g * 4 + 2], acc2);
        acc3 = fmaf(wv.w, Drow[g * 4 + 3], acc3);
      }
      // current chunk: register wc, same grouping as original
      #pragma unroll
      for (int lg = 0; lg + 4 <= li; lg += 4) {
        acc0 = fmaf(wc[lg + 0], Drow[C + lg + 0], acc0);
        acc1 = fmaf(wc[lg + 1], Drow[C + lg + 1], acc1);
        acc2 = fmaf(wc[lg + 2], Drow[C + lg + 2], acc2);
        acc3 = fmaf(wc[lg + 3], Drow[C + lg + 3], acc3);
      }
      #pragma unroll
      for (int lj = li & ~3; lj < li; ++lj) acc0 = fmaf(wc[lj], Drow[C + lj], acc0);
      float zv = ((acc0 + acc1) + (acc2 + acc3)) / Lam[i];
      float az = fabsf(zv);
      float e = __expf(-2.0f * az);
      float th = (1.0f - e) / (1.0f + e);
      float wi = copysignf(th, zv);
      wc[li] = wi;
      wl[(i >> 2) * 260 + t * 4 + (i & 3)] = wi;
      wT[i * BATCH + b] = wi;
    }
  }
}

// ---------------- y = w@W1^T + u@W2^T + bias ----------------
__global__ __launch_bounds__(256) void k_y(const float* __restrict__ wT, const float* __restrict__ u,
                                           const float* __restrict__ W1, const float* __restrict__ W2,
                                           const float* __restrict__ bias, float* __restrict__ y) {
  __shared__ float sA[32][65];
  __shared__ float sW[32][65];
  const int t = threadIdx.x;
  const int b0 = blockIdx.x * 64, o0 = blockIdx.y * 64;
  const int tn = t & 15, tm = t >> 4;
  float acc[4][4] = {};
  for (int k0 = 0; k0 < 128; k0 += 32) {
    #pragma unroll
    for (int l = 0; l < 2; ++l) {
      int idx = t + l * 256;
      int kk = idx >> 4, c4 = (idx & 15) << 2;
      float4 v = *(const float4*)&wT[(k0 + kk) * BATCH + b0 + c4];
      sA[kk][c4 + 0] = v.x; sA[kk][c4 + 1] = v.y; sA[kk][c4 + 2] = v.z; sA[kk][c4 + 3] = v.w;
      int row = idx >> 3, k4 = (idx & 7) << 2;
      float4 d = *(const float4*)&W1[(o0 + row) * 128 + k0 + k4];
      sW[k4 + 0][row] = d.x; sW[k4 + 1][row] = d.y; sW[k4 + 2][row] = d.z; sW[k4 + 3][row] = d.w;
    }
    __syncthreads();
    #pragma unroll
    for (int kk = 0; kk < 32; ++kk) {
      float mm[4], nn[4];
      #pragma unroll
      for (int q = 0; q < 4; ++q) mm[q] = sA[kk][tm * 4 + q];
      #pragma unroll
      for (int q = 0; q < 4; ++q) nn[q] = sW[kk][tn * 4 + q];
      #pragma unroll
      for (int r = 0; r < 4; ++r)
        #pragma unroll
        for (int c = 0; c < 4; ++c)
          acc[r][c] = fmaf(mm[r], nn[c], acc[r][c]);
    }
    __syncthreads();
  }
  for (int k0 = 0; k0 < 128; k0 += 32) {
    #pragma unroll
    for (int l = 0; l < 2; ++l) {
      int idx = t + l * 256;
      int row = idx >> 3, k4 = (idx & 7) << 2;
      float4 v = *(const float4*)&u[(b0 + row) * 128 + k0 + k4];
      sA[k4 + 0][row] = v.x; sA[k4 + 1][row] = v.y; sA[k4 + 2][row] = v.z; sA[k4 + 3][row] = v.w;
      float4 d = *(const float4*)&W2[(o0 + row) * 128 + k0 + k4];
      sW[k4 + 0][row] = d.x; sW[k4 + 1][row] = d.y; sW[k4 + 2][row] = d.z; sW[k4 + 3][row] = d.w;
    }
    __syncthreads();
    #pragma unroll
    for (int kk = 0; kk < 32; ++kk) {
      float mm[4], nn[4];
      #pragma unroll
      for (int q = 0; q < 4; ++q) mm[q] = sA[kk][tm * 4 + q];
      #pragma unroll
      for (int q = 0; q < 4; ++q) nn[q] = sW[kk][tn * 4 + q];
      #pragma unroll
      for (int r = 0; r < 4; ++r)
        #pragma unroll
        for (int c = 0; c < 4; ++c)
          acc[r][c] = fmaf(mm[r], nn[c], acc[r][c]);
    }
    __syncthreads();
  }
  #pragma unroll
  for (int r = 0; r < 4; ++r) {
    int bb = b0 + tm * 4 + r;
    float4 v = make_float4(acc[r][0] + bias[o0 + tn * 4 + 0],
                           acc[r][1] + bias[o0 + tn * 4 + 1],
                           acc[r][2] + bias[o0 + tn * 4 + 2],
                           acc[r][3] + bias[o0 + tn * 4 + 3]);
    *(float4*)&y[bb * 128 + o0 + tn * 4] = v;
  }
}

extern "C" void kernel_launch(void* const* d_in, const int* in_sizes, int n_in,
                              void* d_out, int out_size, void* d_ws, size_t ws_size,
                              hipStream_t stream) {
  const float* u   = (const float*)d_in[0];
  const float* X   = (const float*)d_in[1];
  const float* Y   = (const float*)d_in[2];
  const float* B2  = (const float*)d_in[3];
  const float* C2  = (const float*)d_in[4];
  const float* D21 = (const float*)d_in[5];
  const float* D22 = (const float*)d_in[6];
  const float* D12 = (const float*)d_in[7];
  const float* x0  = (const float*)d_in[8];

  float* ws = (float*)d_ws;
  float* H     = ws;                    // 1327104
  float* M     = H + 1327104;           // 512*640 = 327680
  float* Gt    = M + 327680;            // 65536
  float* W1    = Gt + 65536;            // 16384
  float* W2    = W1 + 16384;            // 16384
  float* D11   = W2 + 16384;            // 16384
  float* Lam   = D11 + 16384;           // 128
  float* xc    = Lam + 128;             // 128
  float* Fx    = xc + 128;              // 512
  float* bias  = Fx + 512;              // 128
  float* baseT = bias + 128 + 64;       // 128*16384 = 2097152
  float* wT    = baseT;                 // in-place
  // Dfac / invUg alias the dead H11 region (H rows 0..511 cols 0..511 are only read by
  // k_assemble, stream-ordered before the LU). 2 * 8 * 64*64 = 65536 floats = ~57 H-rows.
  float* Dfac  = H;
  float* invUg = H + 32768;
  float* y     = (float*)d_out;

  k_xtx<<<dim3(18, 18), 256, 0, stream>>>(X, H);
  k_assemble<<<388, 256, 0, stream>>>(H, Y, C2, x0, M, D11, Lam, xc, Fx);

  for (int kb = 0; kb < 8; ++kb) {
    k_lu_dp<<<16 - 2 * kb, 64, 0, stream>>>(M, Dfac, kb);
    if (kb < 7)
      k_lu_trailing<<<dim3(9 - kb, 7 - kb), 256, 0, stream>>>(M, kb);
  }

  k_inv<<<8, 64, 0, stream>>>(Dfac, invUg);
  k_bs<<<8, 512, 0, stream>>>(M, invUg, Gt);
  k_wass<<<129, 256, 0, stream>>>(Gt, H, B2, D21, D22, Fx, W1, W2, bias);

  k_ud<<<dim3(256, 2), 256, 0, stream>>>(u, D12, xc, baseT);
  k_scan<<<256, 64, 0, stream>>>(baseT, D11, Lam, wT);
  k_y<<<dim3(256, 2), 256, 0, stream>>>(wT, u, W1, W2, bias, y);
}

// Round 11
// 902.450 us; speedup vs baseline: 1.0531x; 1.0531x over previous
//
#include <hip/hip_runtime.h>
#include <math.h>

#define EPS_C 0.001f
#define BATCH 16384

// ---------------- H = X^T X + eps*I  (1152x1152), symmetric: compute bi<=bj, mirror ----------------
__global__ __launch_bounds__(256) void k_xtx(const float* __restrict__ X, float* __restrict__ H) {
  __shared__ float smem[64 * 65];
  const int bi64 = blockIdx.x, bj64 = blockIdx.y;
  if (bi64 > bj64) return;
  float (*sA)[65] = (float(*)[65])smem;
  float (*sB)[65] = (float(*)[65])(smem + 32 * 65);
  const int t = threadIdx.x;
  const int bi = bi64 * 64, bj = bj64 * 64;
  const int tj = t & 15, ti = t >> 4;
  float acc[4][4] = {};
  for (int k0 = 0; k0 < 1152; k0 += 32) {
    #pragma unroll
    for (int l = 0; l < 2; ++l) {
      int idx = t + l * 256;
      int kk = idx >> 4, c4 = (idx & 15) << 2;
      float4 va = *(const float4*)&X[(k0 + kk) * 1152 + bi + c4];
      sA[kk][c4 + 0] = va.x; sA[kk][c4 + 1] = va.y; sA[kk][c4 + 2] = va.z; sA[kk][c4 + 3] = va.w;
      float4 vb = *(const float4*)&X[(k0 + kk) * 1152 + bj + c4];
      sB[kk][c4 + 0] = vb.x; sB[kk][c4 + 1] = vb.y; sB[kk][c4 + 2] = vb.z; sB[kk][c4 + 3] = vb.w;
    }
    __syncthreads();
    #pragma unroll
    for (int kk = 0; kk < 32; ++kk) {
      float am[4], bn[4];
      #pragma unroll
      for (int q = 0; q < 4; ++q) am[q] = sA[kk][ti * 4 + q];
      #pragma unroll
      for (int q = 0; q < 4; ++q) bn[q] = sB[kk][tj * 4 + q];
      #pragma unroll
      for (int r = 0; r < 4; ++r)
        #pragma unroll
        for (int c = 0; c < 4; ++c)
          acc[r][c] = fmaf(am[r], bn[c], acc[r][c]);
    }
    __syncthreads();
  }
  #pragma unroll
  for (int r = 0; r < 4; ++r) {
    int gi = bi + ti * 4 + r;
    float vv[4];
    #pragma unroll
    for (int c = 0; c < 4; ++c) {
      vv[c] = acc[r][c];
      if (gi == bj + tj * 4 + c) vv[c] += EPS_C;
    }
    float4 o = make_float4(vv[0], vv[1], vv[2], vv[3]);
    *(float4*)&H[gi * 1152 + bj + tj * 4] = o;
  }
  if (bi64 < bj64) {
    float (*tr)[65] = (float(*)[65])smem;
    #pragma unroll
    for (int r = 0; r < 4; ++r)
      #pragma unroll
      for (int c = 0; c < 4; ++c)
        tr[tj * 4 + c][ti * 4 + r] = acc[r][c];
    __syncthreads();
    #pragma unroll
    for (int l = 0; l < 4; ++l) {
      int e = t + l * 256;
      int row = e >> 4, c4 = (e & 15) << 2;
      float4 o = make_float4(tr[row][c4], tr[row][c4 + 1], tr[row][c4 + 2], tr[row][c4 + 3]);
      *(float4*)&H[(bj + row) * 1152 + bi + c4] = o;
    }
  }
}

// ---------------- assemble M=[E^T | C2^T], D11, Lam, xc, Fx ----------------
__global__ __launch_bounds__(256) void k_assemble(const float* __restrict__ H, const float* __restrict__ Y,
                           const float* __restrict__ C2, const float* __restrict__ x0,
                           float* __restrict__ M, float* __restrict__ D11,
                           float* __restrict__ Lam, float* __restrict__ xc, float* __restrict__ Fx) {
  const int b = blockIdx.x;
  const int t = threadIdx.x;
  if (b < 256) {
    __shared__ float tA[32][33], tB[32][33], tC[32][33];
    const int R0 = (b & 15) * 32, C0 = (b >> 4) * 32;
    const int c = t & 31, rr = t >> 5;
    #pragma unroll
    for (int p = 0; p < 4; ++p) {
      int row = rr + p * 8;
      tA[row][c] = H[(C0 + row) * 1152 + R0 + c];
      tB[row][c] = H[(640 + C0 + row) * 1152 + 640 + R0 + c];
      tC[row][c] = Y[(C0 + row) * 512 + R0 + c];
    }
    __syncthreads();
    #pragma unroll
    for (int p = 0; p < 4; ++p) {
      int r = rr + p * 8;
      float val = 0.5f * (tA[c][r] + tB[c][r] + tC[c][r] - Y[(R0 + r) * 512 + C0 + c]);
      M[(R0 + r) * 640 + C0 + c] = val;
    }
  } else if (b < 320) {
    int e0 = (b - 256) * 1024;
    #pragma unroll
    for (int l = 0; l < 4; ++l) {
      int e = e0 + l * 256 + t;
      int r = e >> 7, o = e & 127;
      M[r * 640 + 512 + o] = C2[o * 512 + r];
    }
  } else if (b < 384) {
    int e = (b - 320) * 256 + t;
    int i = e >> 7, j = e & 127;
    D11[e] = (j < i) ? -H[(512 + i) * 1152 + 512 + j] : 0.0f;
  } else if (b == 384) {
    if (t < 128) Lam[t] = 0.5f * H[(512 + t) * 1152 + 512 + t];
  } else if (b == 385) {
    if (t < 128) {
      float s = 0.f;
      for (int a = 0; a < 512; ++a) s = fmaf(H[(512 + t) * 1152 + a], x0[a], s);
      xc[t] = -s;
    }
  } else {
    int r = (b - 386) * 256 + t;
    float s = 0.f;
    for (int a = 0; a < 512; ++a) s = fmaf(H[(640 + r) * 1152 + a], x0[a], s);
    Fx[r] = s;
  }
}

// ---------------- fused diag+panels: every block redundantly factors the 64x64 diag in registers
//                  (no inter-block sync); block 0 persists factored diag to Dfac (NOT in-place: race-free) ----------------
__global__ __launch_bounds__(64) void k_lu_dp(float* __restrict__ M, float* __restrict__ Dfac, int kb) {
  __shared__ float sD[64 * 65];
  __shared__ float sRD[64];
  const int t = threadIdx.x;
  const int nU = 9 - kb;
  const int pb = blockIdx.x;
  // issue panel loads early (panel strips are untouched by the diag factor)
  float v[64];
  int c = 0, rr = 0;
  if (pb < nU) {
    c = 64 * (kb + 1) + pb * 64 + t;
    #pragma unroll
    for (int i = 0; i < 64; ++i) v[i] = M[(kb * 64 + i) * 640 + c];
  } else {
    rr = 64 * (kb + 1) + (pb - nU) * 64 + t;
    #pragma unroll
    for (int i = 0; i < 16; ++i) *(float4*)&v[i * 4] = *(const float4*)&M[rr * 640 + kb * 64 + i * 4];
  }
  // redundant in-register LU factor of diag (reads ORIGINAL M diag; M's diag is never overwritten)
  {
    const float* blk = M + kb * 64 * 640 + kb * 64;
    float col[64];
    #pragma unroll
    for (int r = 0; r < 64; ++r) col[r] = blk[r * 640 + t];
    float invp = 1.0f;
    #pragma unroll
    for (int k = 0; k < 64; ++k) {
      float piv = __shfl(col[k], k);
      float inv = 1.0f / piv;
      if (t == k) invp = inv;
      float m = col[k] * inv;
      bool act = t > k;
      #pragma unroll
      for (int r = k + 1; r < 64; ++r) {
        float ckr = __shfl(col[r], k);
        if (act) col[r] -= ckr * m;
      }
    }
    #pragma unroll
    for (int r = 0; r < 64; ++r) {
      if (r > t) col[r] *= invp;
      sD[r * 65 + t] = col[r];
      if (pb == 0) Dfac[kb * 4096 + r * 64 + t] = col[r];
    }
    sRD[t] = invp;  // == 1/sD[t*65+t] bitwise
  }
  __syncthreads();
  if (pb < nU) {
    #pragma unroll
    for (int i = 1; i < 64; ++i) {
      float a0 = v[i], a1 = 0.f;
      #pragma unroll
      for (int j = 0; j < i; j += 2) {
        a0 = fmaf(-sD[i * 65 + j], v[j], a0);
        if (j + 1 < i) a1 = fmaf(-sD[i * 65 + j + 1], v[j + 1], a1);
      }
      v[i] = a0 + a1;
    }
    #pragma unroll
    for (int i = 0; i < 64; ++i) M[(kb * 64 + i) * 640 + c] = v[i];
  } else {
    #pragma unroll
    for (int j = 0; j < 64; ++j) {
      float a0 = v[j], a1 = 0.f;
      #pragma unroll
      for (int i = 0; i < j; i += 2) {
        a0 = fmaf(-v[i], sD[i * 65 + j], a0);
        if (i + 1 < j) a1 = fmaf(-v[i + 1], sD[(i + 1) * 65 + j], a1);
      }
      v[j] = (a0 + a1) * sRD[j];
    }
    #pragma unroll
    for (int i = 0; i < 16; ++i) *(float4*)&M[rr * 640 + kb * 64 + i * 4] = *(float4*)&v[i * 4];
  }
}

// ---------------- trailing update: A22 -= L21 * U12 (cols include augmented) ----------------
__global__ __launch_bounds__(256) void k_lu_trailing(float* __restrict__ M, int kb) {
  __shared__ float sL[32][65];
  __shared__ float sU[32][65];
  const int t = threadIdx.x;
  const int base = 64 * (kb + 1);
  const int r0 = base + blockIdx.y * 64, c0 = base + blockIdx.x * 64;
  const int tj = t & 15, ti = t >> 4;
  float acc[4][4] = {};
  for (int k0 = 0; k0 < 64; k0 += 32) {
    #pragma unroll
    for (int l = 0; l < 2; ++l) {
      int idx = t + l * 256;
      int row = idx >> 3, k4 = (idx & 7) << 2;
      float4 v = *(const float4*)&M[(r0 + row) * 640 + kb * 64 + k0 + k4];
      sL[k4 + 0][row] = v.x; sL[k4 + 1][row] = v.y; sL[k4 + 2][row] = v.z; sL[k4 + 3][row] = v.w;
      int kk = idx >> 4, c4 = (idx & 15) << 2;
      float4 u4 = *(const float4*)&M[(kb * 64 + k0 + kk) * 640 + c0 + c4];
      sU[kk][c4 + 0] = u4.x; sU[kk][c4 + 1] = u4.y; sU[kk][c4 + 2] = u4.z; sU[kk][c4 + 3] = u4.w;
    }
    __syncthreads();
    #pragma unroll
    for (int kk = 0; kk < 32; ++kk) {
      float am[4], bn[4];
      #pragma unroll
      for (int q = 0; q < 4; ++q) am[q] = sL[kk][ti * 4 + q];
      #pragma unroll
      for (int q = 0; q < 4; ++q) bn[q] = sU[kk][tj * 4 + q];
      #pragma unroll
      for (int r = 0; r < 4; ++r)
        #pragma unroll
        for (int c = 0; c < 4; ++c)
          acc[r][c] = fmaf(am[r], bn[c], acc[r][c]);
    }
    __syncthreads();
  }
  #pragma unroll
  for (int r = 0; r < 4; ++r) {
    float4 old = *(float4*)&M[(r0 + ti * 4 + r) * 640 + c0 + tj * 4];
    old.x -= acc[r][0]; old.y -= acc[r][1]; old.z -= acc[r][2]; old.w -= acc[r][3];
    *(float4*)&M[(r0 + ti * 4 + r) * 640 + c0 + tj * 4] = old;
  }
}

// ---------------- invert each factored 64x64 diag block: invU[kb] = U_kk^-1 (8 parallel blocks) ----------------
__global__ __launch_bounds__(64) void k_inv(const float* __restrict__ Dfac, float* __restrict__ invU) {
  __shared__ float sD[64 * 65];
  __shared__ float srs[64];
  const int t = threadIdx.x;
  const int kb = blockIdx.x;
  for (int l = 0; l < 64; ++l) sD[l * 65 + t] = Dfac[kb * 4096 + l * 64 + t];
  __syncthreads();
  srs[t] = 1.0f / sD[t * 65 + t];
  __syncthreads();
  // column t of U^-1 via back-substitution, fully unrolled, registers only
  float v[64];
  #pragma unroll
  for (int i = 0; i < 64; ++i) v[i] = (i == t) ? srs[t] : 0.0f;
  #pragma unroll
  for (int i = 62; i >= 0; --i) {
    float a0 = 0.f, a1 = 0.f;
    #pragma unroll
    for (int j = i + 1; j < 64; j += 2) {
      a0 = fmaf(-sD[i * 65 + j], v[j], a0);
      if (j + 1 < 64) a1 = fmaf(-sD[i * 65 + j + 1], v[j + 1], a1);
    }
    float nv = (a0 + a1) * srs[i];
    v[i] = (i == t) ? v[i] : nv;   // nv==0 naturally for i>t (strictly-upper zeros)
  }
  #pragma unroll
  for (int i = 0; i < 64; ++i) invU[kb * 4096 + i * 64 + t] = v[i];
}

// ---------------- backward solve U * Gt = Z : 8 INDEPENDENT column-slice blocks (16 cols each) ----------------
__global__ __launch_bounds__(512, 2) void k_bs(const float* __restrict__ M, const float* __restrict__ invUg,
                                               float* __restrict__ Gt) {
  __shared__ float sZ[512 * 17];     // 512 rows x 16 cols, stride 17 (bank-spread)
  __shared__ float sU[64 * 65];
  __shared__ float sI[64 * 65];      // padded: (i*65+k)%32 varies with i
  const int t = threadIdx.x;
  const int c0 = blockIdx.x * 16;
  const int o = t & 15, q = t >> 4;  // q in [0,32): row-thread groups
  // load this block's Z slice (augmented columns of M)
  #pragma unroll
  for (int l = 0; l < 16; ++l) {
    int e = t + l * 512;
    int r = e >> 4, oo = e & 15;
    sZ[r * 17 + oo] = M[r * 640 + 512 + c0 + oo];
  }
  for (int kb = 7; kb >= 0; --kb) {
    // stage invU(kb), padded stride
    #pragma unroll
    for (int l = 0; l < 8; ++l) {
      int e = t + l * 512;
      int r = e >> 6, k = e & 63;
      sI[r * 65 + k] = invUg[kb * 4096 + r * 64 + k];
    }
    __syncthreads();   // covers initial sZ load (first iter) + sI staging + prior updates
    // x_kb = invU @ z_kb : read phase
    float xv[2];
    #pragma unroll
    for (int rr = 0; rr < 2; ++rr) {
      int i = q * 2 + rr;
      float a0 = 0.f, a1 = 0.f;
      #pragma unroll
      for (int k = 0; k < 64; k += 2) {
        a0 = fmaf(sI[i * 65 + k], sZ[(kb * 64 + k) * 17 + o], a0);
        a1 = fmaf(sI[i * 65 + k + 1], sZ[(kb * 64 + k + 1) * 17 + o], a1);
      }
      xv[rr] = a0 + a1;
    }
    __syncthreads();   // all reads of z_kb done before overwrite
    #pragma unroll
    for (int rr = 0; rr < 2; ++rr) {
      int i = q * 2 + rr;
      sZ[(kb * 64 + i) * 17 + o] = xv[rr];
      Gt[(kb * 64 + i) * 128 + c0 + o] = xv[rr];
    }
    __syncthreads();
    if (kb == 0) break;
    // hoist x_kb into registers once (each thread: its own column o) -- STATIC indices only
    float xk[64];
    #pragma unroll
    for (int k = 0; k < 64; ++k) xk[k] = sZ[(kb * 64 + k) * 17 + o];
    // updates: z_i -= U(i,kb) @ x_kb for i < kb, with reg-staged double-buffered U tiles
    float bufA[8], bufB[8];
    #pragma unroll
    for (int l = 0; l < 8; ++l) {
      int e = t + l * 512;
      int r = e >> 6, k = e & 63;
      bufA[l] = M[r * 640 + kb * 64 + k];          // i = 0 tile
    }
    for (int i = 0; i < kb; ++i) {
      #pragma unroll
      for (int l = 0; l < 8; ++l) {
        int e = t + l * 512;
        int r = e >> 6, k = e & 63;
        sU[r * 65 + k] = bufA[l];
      }
      if (i + 1 < kb) {
        #pragma unroll
        for (int l = 0; l < 8; ++l) {
          int e = t + l * 512;
          int r = e >> 6, k = e & 63;
          bufB[l] = M[((i + 1) * 64 + r) * 640 + kb * 64 + k];   // prefetch next tile
        }
      }
      __syncthreads();
      #pragma unroll
      for (int rr = 0; rr < 2; ++rr) {
        int row = q * 2 + rr;
        float acc = sZ[(i * 64 + row) * 17 + o];
        #pragma unroll
        for (int k = 0; k < 64; ++k)
          acc = fmaf(-sU[row * 65 + k], xk[k], acc);
        sZ[(i * 64 + row) * 17 + o] = acc;
      }
      #pragma unroll
      for (int l = 0; l < 8; ++l) bufA[l] = bufB[l];
      __syncthreads();   // compute done reading sU before next iteration overwrites it
    }
  }
}

// ---------------- W1 = G@B1 + D21, W2 = G@B2 + D22, bias = G@Fx ----------------
__global__ void k_wass(const float* __restrict__ Gt, const float* __restrict__ H,
                       const float* __restrict__ B2, const float* __restrict__ D21,
                       const float* __restrict__ D22, const float* __restrict__ Fx,
                       float* __restrict__ W1, float* __restrict__ W2, float* __restrict__ bias) {
  int idx = blockIdx.x * 256 + threadIdx.x;
  if (idx < 16384) {
    int o = idx >> 7, j = idx & 127;
    float s = 0.f;
    for (int a = 0; a < 512; ++a) s = fmaf(Gt[a * 128 + o], H[(640 + a) * 1152 + 512 + j], s);
    W1[idx] = s + D21[idx];
  } else if (idx < 32768) {
    int q = idx - 16384;
    int o = q >> 7, j = q & 127;
    float s = 0.f;
    for (int a = 0; a < 512; ++a) s = fmaf(Gt[a * 128 + o], B2[a * 128 + j], s);
    W2[q] = s + D22[q];
  } else if (idx < 32768 + 128) {
    int o = idx - 32768;
    float s = 0.f;
    for (int a = 0; a < 512; ++a) s = fmaf(Gt[a * 128 + o], Fx[a], s);
    bias[o] = s;
  }
}

// ---------------- baseT[i][b] = xc[i] + (u @ D12^T)[b][i] ----------------
__global__ __launch_bounds__(256) void k_ud(const float* __restrict__ u, const float* __restrict__ D12,
                                            const float* __restrict__ xc, float* __restrict__ baseT) {
  __shared__ float sU[32][65];
  __shared__ float sD[32][65];
  const int t = threadIdx.x;
  const int b0 = blockIdx.x * 64, i0 = blockIdx.y * 64;
  const int tm = t & 15, tn = t >> 4;
  float acc[4][4] = {};
  for (int k0 = 0; k0 < 128; k0 += 32) {
    #pragma unroll
    for (int l = 0; l < 2; ++l) {
      int idx = t + l * 256;
      int row = idx >> 3, k4 = (idx & 7) << 2;
      float4 v = *(const float4*)&u[(b0 + row) * 128 + k0 + k4];
      sU[k4 + 0][row] = v.x; sU[k4 + 1][row] = v.y; sU[k4 + 2][row] = v.z; sU[k4 + 3][row] = v.w;
      float4 d = *(const float4*)&D12[(i0 + row) * 128 + k0 + k4];
      sD[k4 + 0][row] = d.x; sD[k4 + 1][row] = d.y; sD[k4 + 2][row] = d.z; sD[k4 + 3][row] = d.w;
    }
    __syncthreads();
    #pragma unroll
    for (int kk = 0; kk < 32; ++kk) {
      float mm[4], nn[4];
      #pragma unroll
      for (int q = 0; q < 4; ++q) mm[q] = sU[kk][tm * 4 + q];
      #pragma unroll
      for (int q = 0; q < 4; ++q) nn[q] = sD[kk][tn * 4 + q];
      #pragma unroll
      for (int c = 0; c < 4; ++c)
        #pragma unroll
        for (int r = 0; r < 4; ++r)
          acc[c][r] = fmaf(nn[c], mm[r], acc[c][r]);
    }
    __syncthreads();
  }
  #pragma unroll
  for (int c = 0; c < 4; ++c) {
    int i = i0 + tn * 4 + c;
    float xcv = xc[i];
    float4 v = make_float4(acc[c][0] + xcv, acc[c][1] + xcv, acc[c][2] + xcv, acc[c][3] + xcv);
    *(float4*)&baseT[i * BATCH + b0 + tm * 4] = v;
  }
}

// ---------------- scan: w[i] = tanh((base_i + sum_{j<i} D11[i][j] w[j]) / Lam[i]) ----------------
// Decoupled-history version. Per 16-step chunk:
//  (1) hist[16] = 16 INDEPENDENT dot-products of completed history vs the 16 upcoming D11 rows
//      -- one ds_read_b128 per 4 history terms, REUSED by all 16 targets (112 LDS reads/thread
//      total vs 1792 in round 10), 16-way ILP so latency is pipelined, OFF the serial chain.
//  (2) serial 16-step scan touching only register wc[16] (<=15 fmaf + tanh per step).
//  (3) publish chunk: contiguous float4 LDS writes (conflict-free; round-10's per-step scalar
//      writes were 8-way conflicts -> SQ_LDS_BANK_CONFLICT=196608) + coalesced wT stores.
__global__ __launch_bounds__(64, 1) void k_scan(const float* __restrict__ baseT, const float* __restrict__ D11g,
                                                const float* __restrict__ Lam, float* __restrict__ wT) {
  __shared__ float wl[32 * 260];   // 32 groups x (64 threads x 4 elems + 4 pad)
  const int t = threadIdx.x;
  const int b = blockIdx.x * 64 + t;
  for (int c = 0; c < 8; ++c) {
    const int C = c * 16;
    float bt[16];
    #pragma unroll
    for (int l = 0; l < 16; ++l) bt[l] = baseT[(C + l) * BATCH + b];
    float hist[16];
    #pragma unroll
    for (int l = 0; l < 16; ++l) hist[l] = 0.f;
    for (int g = 0; g < C / 4; ++g) {
      float4 wv = *(const float4*)&wl[g * 260 + t * 4];
      #pragma unroll
      for (int li = 0; li < 16; ++li) {
        const float* __restrict__ Dr = D11g + (C + li) * 128 + g * 4;
        float h = hist[li];
        h = fmaf(wv.x, Dr[0], h);
        h = fmaf(wv.y, Dr[1], h);
        h = fmaf(wv.z, Dr[2], h);
        h = fmaf(wv.w, Dr[3], h);
        hist[li] = h;
      }
    }
    float wc[16];
    #pragma unroll
    for (int li = 0; li < 16; ++li) {
      const int i = C + li;
      const float* __restrict__ Drow = D11g + i * 128;
      float a0 = bt[li], a1 = hist[li], a2 = 0.f, a3 = 0.f;
      #pragma unroll
      for (int lg = 0; lg + 4 <= li; lg += 4) {
        a0 = fmaf(wc[lg + 0], Drow[C + lg + 0], a0);
        a1 = fmaf(wc[lg + 1], Drow[C + lg + 1], a1);
        a2 = fmaf(wc[lg + 2], Drow[C + lg + 2], a2);
        a3 = fmaf(wc[lg + 3], Drow[C + lg + 3], a3);
      }
      #pragma unroll
      for (int lj = li & ~3; lj < li; ++lj) a0 = fmaf(wc[lj], Drow[C + lj], a0);
      float zv = ((a0 + a1) + (a2 + a3)) / Lam[i];
      float az = fabsf(zv);
      float e = __expf(-2.0f * az);
      float th = (1.0f - e) / (1.0f + e);
      wc[li] = copysignf(th, zv);
    }
    #pragma unroll
    for (int gg = 0; gg < 4; ++gg) {
      float4 o = make_float4(wc[gg * 4 + 0], wc[gg * 4 + 1], wc[gg * 4 + 2], wc[gg * 4 + 3]);
      *(float4*)&wl[(C / 4 + gg) * 260 + t * 4] = o;
    }
    #pragma unroll
    for (int li = 0; li < 16; ++li) wT[(C + li) * BATCH + b] = wc[li];
  }
}

// ---------------- y = w@W1^T + u@W2^T + bias ----------------
__global__ __launch_bounds__(256) void k_y(const float* __restrict__ wT, const float* __restrict__ u,
                                           const float* __restrict__ W1, const float* __restrict__ W2,
                                           const float* __restrict__ bias, float* __restrict__ y) {
  __shared__ float sA[32][65];
  __shared__ float sW[32][65];
  const int t = threadIdx.x;
  const int b0 = blockIdx.x * 64, o0 = blockIdx.y * 64;
  const int tn = t & 15, tm = t >> 4;
  float acc[4][4] = {};
  for (int k0 = 0; k0 < 128; k0 += 32) {
    #pragma unroll
    for (int l = 0; l < 2; ++l) {
      int idx = t + l * 256;
      int kk = idx >> 4, c4 = (idx & 15) << 2;
      float4 v = *(const float4*)&wT[(k0 + kk) * BATCH + b0 + c4];
      sA[kk][c4 + 0] = v.x; sA[kk][c4 + 1] = v.y; sA[kk][c4 + 2] = v.z; sA[kk][c4 + 3] = v.w;
      int row = idx >> 3, k4 = (idx & 7) << 2;
      float4 d = *(const float4*)&W1[(o0 + row) * 128 + k0 + k4];
      sW[k4 + 0][row] = d.x; sW[k4 + 1][row] = d.y; sW[k4 + 2][row] = d.z; sW[k4 + 3][row] = d.w;
    }
    __syncthreads();
    #pragma unroll
    for (int kk = 0; kk < 32; ++kk) {
      float mm[4], nn[4];
      #pragma unroll
      for (int q = 0; q < 4; ++q) mm[q] = sA[kk][tm * 4 + q];
      #pragma unroll
      for (int q = 0; q < 4; ++q) nn[q] = sW[kk][tn * 4 + q];
      #pragma unroll
      for (int r = 0; r < 4; ++r)
        #pragma unroll
        for (int c = 0; c < 4; ++c)
          acc[r][c] = fmaf(mm[r], nn[c], acc[r][c]);
    }
    __syncthreads();
  }
  for (int k0 = 0; k0 < 128; k0 += 32) {
    #pragma unroll
    for (int l = 0; l < 2; ++l) {
      int idx = t + l * 256;
      int row = idx >> 3, k4 = (idx & 7) << 2;
      float4 v = *(const float4*)&u[(b0 + row) * 128 + k0 + k4];
      sA[k4 + 0][row] = v.x; sA[k4 + 1][row] = v.y; sA[k4 + 2][row] = v.z; sA[k4 + 3][row] = v.w;
      float4 d = *(const float4*)&W2[(o0 + row) * 128 + k0 + k4];
      sW[k4 + 0][row] = d.x; sW[k4 + 1][row] = d.y; sW[k4 + 2][row] = d.z; sW[k4 + 3][row] = d.w;
    }
    __syncthreads();
    #pragma unroll
    for (int kk = 0; kk < 32; ++kk) {
      float mm[4], nn[4];
      #pragma unroll
      for (int q = 0; q < 4; ++q) mm[q] = sA[kk][tm * 4 + q];
      #pragma unroll
      for (int q = 0; q < 4; ++q) nn[q] = sW[kk][tn * 4 + q];
      #pragma unroll
      for (int r = 0; r < 4; ++r)
        #pragma unroll
        for (int c = 0; c < 4; ++c)
          acc[r][c] = fmaf(mm[r], nn[c], acc[r][c]);
    }
    __syncthreads();
  }
  #pragma unroll
  for (int r = 0; r < 4; ++r) {
    int bb = b0 + tm * 4 + r;
    float4 v = make_float4(acc[r][0] + bias[o0 + tn * 4 + 0],
                           acc[r][1] + bias[o0 + tn * 4 + 1],
                           acc[r][2] + bias[o0 + tn * 4 + 2],
                           acc[r][3] + bias[o0 + tn * 4 + 3]);
    *(float4*)&y[bb * 128 + o0 + tn * 4] = v;
  }
}

extern "C" void kernel_launch(void* const* d_in, const int* in_sizes, int n_in,
                              void* d_out, int out_size, void* d_ws, size_t ws_size,
                              hipStream_t stream) {
  const float* u   = (const float*)d_in[0];
  const float* X   = (const float*)d_in[1];
  const float* Y   = (const float*)d_in[2];
  const float* B2  = (const float*)d_in[3];
  const float* C2  = (const float*)d_in[4];
  const float* D21 = (const float*)d_in[5];
  const float* D22 = (const float*)d_in[6];
  const float* D12 = (const float*)d_in[7];
  const float* x0  = (const float*)d_in[8];

  float* ws = (float*)d_ws;
  float* H     = ws;                    // 1327104
  float* M     = H + 1327104;           // 512*640 = 327680
  float* Gt    = M + 327680;            // 65536
  float* W1    = Gt + 65536;            // 16384
  float* W2    = W1 + 16384;            // 16384
  float* D11   = W2 + 16384;            // 16384
  float* Lam   = D11 + 16384;           // 128
  float* xc    = Lam + 128;             // 128
  float* Fx    = xc + 128;              // 512
  float* bias  = Fx + 512;              // 128
  float* baseT = bias + 128 + 64;       // 128*16384 = 2097152
  float* wT    = baseT;                 // in-place
  // Dfac / invUg alias the dead H11 region (H rows 0..511 cols 0..511 are only read by
  // k_assemble, stream-ordered before the LU). 2 * 8 * 64*64 = 65536 floats = ~57 H-rows.
  float* Dfac  = H;
  float* invUg = H + 32768;
  float* y     = (float*)d_out;

  k_xtx<<<dim3(18, 18), 256, 0, stream>>>(X, H);
  k_assemble<<<388, 256, 0, stream>>>(H, Y, C2, x0, M, D11, Lam, xc, Fx);

  for (int kb = 0; kb < 8; ++kb) {
    k_lu_dp<<<16 - 2 * kb, 64, 0, stream>>>(M, Dfac, kb);
    if (kb < 7)
      k_lu_trailing<<<dim3(9 - kb, 7 - kb), 256, 0, stream>>>(M, kb);
  }

  k_inv<<<8, 64, 0, stream>>>(Dfac, invUg);
  k_bs<<<8, 512, 0, stream>>>(M, invUg, Gt);
  k_wass<<<129, 256, 0, stream>>>(Gt, H, B2, D21, D22, Fx, W1, W2, bias);

  k_ud<<<dim3(256, 2), 256, 0, stream>>>(u, D12, xc, baseT);
  k_scan<<<256, 64, 0, stream>>>(baseT, D11, Lam, wT);
  k_y<<<dim3(256, 2), 256, 0, stream>>>(wT, u, W1, W2, bias, y);
}

// Round 12
// 846.480 us; speedup vs baseline: 1.1228x; 1.0661x over previous
//
#include <hip/hip_runtime.h>
#include <math.h>

#define EPS_C 0.001f
#define BATCH 16384

// ---------------- H = X^T X + eps*I  (1152x1152), symmetric: compute bi<=bj, mirror ----------------
__global__ __launch_bounds__(256) void k_xtx(const float* __restrict__ X, float* __restrict__ H) {
  __shared__ float smem[64 * 65];
  const int bi64 = blockIdx.x, bj64 = blockIdx.y;
  if (bi64 > bj64) return;
  float (*sA)[65] = (float(*)[65])smem;
  float (*sB)[65] = (float(*)[65])(smem + 32 * 65);
  const int t = threadIdx.x;
  const int bi = bi64 * 64, bj = bj64 * 64;
  const int tj = t & 15, ti = t >> 4;
  float acc[4][4] = {};
  for (int k0 = 0; k0 < 1152; k0 += 32) {
    #pragma unroll
    for (int l = 0; l < 2; ++l) {
      int idx = t + l * 256;
      int kk = idx >> 4, c4 = (idx & 15) << 2;
      float4 va = *(const float4*)&X[(k0 + kk) * 1152 + bi + c4];
      sA[kk][c4 + 0] = va.x; sA[kk][c4 + 1] = va.y; sA[kk][c4 + 2] = va.z; sA[kk][c4 + 3] = va.w;
      float4 vb = *(const float4*)&X[(k0 + kk) * 1152 + bj + c4];
      sB[kk][c4 + 0] = vb.x; sB[kk][c4 + 1] = vb.y; sB[kk][c4 + 2] = vb.z; sB[kk][c4 + 3] = vb.w;
    }
    __syncthreads();
    #pragma unroll
    for (int kk = 0; kk < 32; ++kk) {
      float am[4], bn[4];
      #pragma unroll
      for (int q = 0; q < 4; ++q) am[q] = sA[kk][ti * 4 + q];
      #pragma unroll
      for (int q = 0; q < 4; ++q) bn[q] = sB[kk][tj * 4 + q];
      #pragma unroll
      for (int r = 0; r < 4; ++r)
        #pragma unroll
        for (int c = 0; c < 4; ++c)
          acc[r][c] = fmaf(am[r], bn[c], acc[r][c]);
    }
    __syncthreads();
  }
  #pragma unroll
  for (int r = 0; r < 4; ++r) {
    int gi = bi + ti * 4 + r;
    float vv[4];
    #pragma unroll
    for (int c = 0; c < 4; ++c) {
      vv[c] = acc[r][c];
      if (gi == bj + tj * 4 + c) vv[c] += EPS_C;
    }
    float4 o = make_float4(vv[0], vv[1], vv[2], vv[3]);
    *(float4*)&H[gi * 1152 + bj + tj * 4] = o;
  }
  if (bi64 < bj64) {
    float (*tr)[65] = (float(*)[65])smem;
    #pragma unroll
    for (int r = 0; r < 4; ++r)
      #pragma unroll
      for (int c = 0; c < 4; ++c)
        tr[tj * 4 + c][ti * 4 + r] = acc[r][c];
    __syncthreads();
    #pragma unroll
    for (int l = 0; l < 4; ++l) {
      int e = t + l * 256;
      int row = e >> 4, c4 = (e & 15) << 2;
      float4 o = make_float4(tr[row][c4], tr[row][c4 + 1], tr[row][c4 + 2], tr[row][c4 + 3]);
      *(float4*)&H[(bj + row) * 1152 + bi + c4] = o;
    }
  }
}

// ---------------- assemble M=[E^T | C2^T], D11, Lam, xc, Fx ----------------
__global__ __launch_bounds__(256) void k_assemble(const float* __restrict__ H, const float* __restrict__ Y,
                           const float* __restrict__ C2, const float* __restrict__ x0,
                           float* __restrict__ M, float* __restrict__ D11,
                           float* __restrict__ Lam, float* __restrict__ xc, float* __restrict__ Fx) {
  const int b = blockIdx.x;
  const int t = threadIdx.x;
  if (b < 256) {
    __shared__ float tA[32][33], tB[32][33], tC[32][33];
    const int R0 = (b & 15) * 32, C0 = (b >> 4) * 32;
    const int c = t & 31, rr = t >> 5;
    #pragma unroll
    for (int p = 0; p < 4; ++p) {
      int row = rr + p * 8;
      tA[row][c] = H[(C0 + row) * 1152 + R0 + c];
      tB[row][c] = H[(640 + C0 + row) * 1152 + 640 + R0 + c];
      tC[row][c] = Y[(C0 + row) * 512 + R0 + c];
    }
    __syncthreads();
    #pragma unroll
    for (int p = 0; p < 4; ++p) {
      int r = rr + p * 8;
      float val = 0.5f * (tA[c][r] + tB[c][r] + tC[c][r] - Y[(R0 + r) * 512 + C0 + c]);
      M[(R0 + r) * 640 + C0 + c] = val;
    }
  } else if (b < 320) {
    int e0 = (b - 256) * 1024;
    #pragma unroll
    for (int l = 0; l < 4; ++l) {
      int e = e0 + l * 256 + t;
      int r = e >> 7, o = e & 127;
      M[r * 640 + 512 + o] = C2[o * 512 + r];
    }
  } else if (b < 384) {
    int e = (b - 320) * 256 + t;
    int i = e >> 7, j = e & 127;
    D11[e] = (j < i) ? -H[(512 + i) * 1152 + 512 + j] : 0.0f;
  } else if (b == 384) {
    if (t < 128) Lam[t] = 0.5f * H[(512 + t) * 1152 + 512 + t];
  } else if (b == 385) {
    if (t < 128) {
      float s = 0.f;
      for (int a = 0; a < 512; ++a) s = fmaf(H[(512 + t) * 1152 + a], x0[a], s);
      xc[t] = -s;
    }
  } else {
    int r = (b - 386) * 256 + t;
    float s = 0.f;
    for (int a = 0; a < 512; ++a) s = fmaf(H[(640 + r) * 1152 + a], x0[a], s);
    Fx[r] = s;
  }
}

// ---------------- fused diag+panels: every block redundantly factors the 64x64 diag in registers
//                  (no inter-block sync); block 0 persists factored diag to Dfac (NOT in-place: race-free) ----------------
__global__ __launch_bounds__(64) void k_lu_dp(float* __restrict__ M, float* __restrict__ Dfac, int kb) {
  __shared__ float sD[64 * 65];
  __shared__ float sRD[64];
  const int t = threadIdx.x;
  const int nU = 9 - kb;
  const int pb = blockIdx.x;
  // issue panel loads early (panel strips are untouched by the diag factor)
  float v[64];
  int c = 0, rr = 0;
  if (pb < nU) {
    c = 64 * (kb + 1) + pb * 64 + t;
    #pragma unroll
    for (int i = 0; i < 64; ++i) v[i] = M[(kb * 64 + i) * 640 + c];
  } else {
    rr = 64 * (kb + 1) + (pb - nU) * 64 + t;
    #pragma unroll
    for (int i = 0; i < 16; ++i) *(float4*)&v[i * 4] = *(const float4*)&M[rr * 640 + kb * 64 + i * 4];
  }
  // redundant in-register LU factor of diag (reads ORIGINAL M diag; M's diag is never overwritten)
  {
    const float* blk = M + kb * 64 * 640 + kb * 64;
    float col[64];
    #pragma unroll
    for (int r = 0; r < 64; ++r) col[r] = blk[r * 640 + t];
    float invp = 1.0f;
    #pragma unroll
    for (int k = 0; k < 64; ++k) {
      float piv = __shfl(col[k], k);
      float inv = 1.0f / piv;
      if (t == k) invp = inv;
      float m = col[k] * inv;
      bool act = t > k;
      #pragma unroll
      for (int r = k + 1; r < 64; ++r) {
        float ckr = __shfl(col[r], k);
        if (act) col[r] -= ckr * m;
      }
    }
    #pragma unroll
    for (int r = 0; r < 64; ++r) {
      if (r > t) col[r] *= invp;
      sD[r * 65 + t] = col[r];
      if (pb == 0) Dfac[kb * 4096 + r * 64 + t] = col[r];
    }
    sRD[t] = invp;  // == 1/sD[t*65+t] bitwise
  }
  __syncthreads();
  if (pb < nU) {
    #pragma unroll
    for (int i = 1; i < 64; ++i) {
      float a0 = v[i], a1 = 0.f;
      #pragma unroll
      for (int j = 0; j < i; j += 2) {
        a0 = fmaf(-sD[i * 65 + j], v[j], a0);
        if (j + 1 < i) a1 = fmaf(-sD[i * 65 + j + 1], v[j + 1], a1);
      }
      v[i] = a0 + a1;
    }
    #pragma unroll
    for (int i = 0; i < 64; ++i) M[(kb * 64 + i) * 640 + c] = v[i];
  } else {
    #pragma unroll
    for (int j = 0; j < 64; ++j) {
      float a0 = v[j], a1 = 0.f;
      #pragma unroll
      for (int i = 0; i < j; i += 2) {
        a0 = fmaf(-v[i], sD[i * 65 + j], a0);
        if (i + 1 < j) a1 = fmaf(-v[i + 1], sD[(i + 1) * 65 + j], a1);
      }
      v[j] = (a0 + a1) * sRD[j];
    }
    #pragma unroll
    for (int i = 0; i < 16; ++i) *(float4*)&M[rr * 640 + kb * 64 + i * 4] = *(float4*)&v[i * 4];
  }
}

// ---------------- trailing update: A22 -= L21 * U12 (cols include augmented) ----------------
__global__ __launch_bounds__(256) void k_lu_trailing(float* __restrict__ M, int kb) {
  __shared__ float sL[32][65];
  __shared__ float sU[32][65];
  const int t = threadIdx.x;
  const int base = 64 * (kb + 1);
  const int r0 = base + blockIdx.y * 64, c0 = base + blockIdx.x * 64;
  const int tj = t & 15, ti = t >> 4;
  float acc[4][4] = {};
  for (int k0 = 0; k0 < 64; k0 += 32) {
    #pragma unroll
    for (int l = 0; l < 2; ++l) {
      int idx = t + l * 256;
      int row = idx >> 3, k4 = (idx & 7) << 2;
      float4 v = *(const float4*)&M[(r0 + row) * 640 + kb * 64 + k0 + k4];
      sL[k4 + 0][row] = v.x; sL[k4 + 1][row] = v.y; sL[k4 + 2][row] = v.z; sL[k4 + 3][row] = v.w;
      int kk = idx >> 4, c4 = (idx & 15) << 2;
      float4 u4 = *(const float4*)&M[(kb * 64 + k0 + kk) * 640 + c0 + c4];
      sU[kk][c4 + 0] = u4.x; sU[kk][c4 + 1] = u4.y; sU[kk][c4 + 2] = u4.z; sU[kk][c4 + 3] = u4.w;
    }
    __syncthreads();
    #pragma unroll
    for (int kk = 0; kk < 32; ++kk) {
      float am[4], bn[4];
      #pragma unroll
      for (int q = 0; q < 4; ++q) am[q] = sL[kk][ti * 4 + q];
      #pragma unroll
      for (int q = 0; q < 4; ++q) bn[q] = sU[kk][tj * 4 + q];
      #pragma unroll
      for (int r = 0; r < 4; ++r)
        #pragma unroll
        for (int c = 0; c < 4; ++c)
          acc[r][c] = fmaf(am[r], bn[c], acc[r][c]);
    }
    __syncthreads();
  }
  #pragma unroll
  for (int r = 0; r < 4; ++r) {
    float4 old = *(float4*)&M[(r0 + ti * 4 + r) * 640 + c0 + tj * 4];
    old.x -= acc[r][0]; old.y -= acc[r][1]; old.z -= acc[r][2]; old.w -= acc[r][3];
    *(float4*)&M[(r0 + ti * 4 + r) * 640 + c0 + tj * 4] = old;
  }
}

// ---------------- invert each factored 64x64 diag block: invU[kb] = U_kk^-1 (8 parallel blocks) ----------------
__global__ __launch_bounds__(64) void k_inv(const float* __restrict__ Dfac, float* __restrict__ invU) {
  __shared__ float sD[64 * 65];
  __shared__ float srs[64];
  const int t = threadIdx.x;
  const int kb = blockIdx.x;
  for (int l = 0; l < 64; ++l) sD[l * 65 + t] = Dfac[kb * 4096 + l * 64 + t];
  __syncthreads();
  srs[t] = 1.0f / sD[t * 65 + t];
  __syncthreads();
  // column t of U^-1 via back-substitution, fully unrolled, registers only
  float v[64];
  #pragma unroll
  for (int i = 0; i < 64; ++i) v[i] = (i == t) ? srs[t] : 0.0f;
  #pragma unroll
  for (int i = 62; i >= 0; --i) {
    float a0 = 0.f, a1 = 0.f;
    #pragma unroll
    for (int j = i + 1; j < 64; j += 2) {
      a0 = fmaf(-sD[i * 65 + j], v[j], a0);
      if (j + 1 < 64) a1 = fmaf(-sD[i * 65 + j + 1], v[j + 1], a1);
    }
    float nv = (a0 + a1) * srs[i];
    v[i] = (i == t) ? v[i] : nv;   // nv==0 naturally for i>t (strictly-upper zeros)
  }
  #pragma unroll
  for (int i = 0; i < 64; ++i) invU[kb * 4096 + i * 64 + t] = v[i];
}

// ---------------- backward solve U * Gt = Z : 8 INDEPENDENT column-slice blocks (16 cols each) ----------------
__global__ __launch_bounds__(512, 2) void k_bs(const float* __restrict__ M, const float* __restrict__ invUg,
                                               float* __restrict__ Gt) {
  __shared__ float sZ[512 * 17];     // 512 rows x 16 cols, stride 17 (bank-spread)
  __shared__ float sU[64 * 65];
  __shared__ float sI[64 * 65];      // padded: (i*65+k)%32 varies with i
  const int t = threadIdx.x;
  const int c0 = blockIdx.x * 16;
  const int o = t & 15, q = t >> 4;  // q in [0,32): row-thread groups
  // load this block's Z slice (augmented columns of M)
  #pragma unroll
  for (int l = 0; l < 16; ++l) {
    int e = t + l * 512;
    int r = e >> 4, oo = e & 15;
    sZ[r * 17 + oo] = M[r * 640 + 512 + c0 + oo];
  }
  for (int kb = 7; kb >= 0; --kb) {
    // stage invU(kb), padded stride
    #pragma unroll
    for (int l = 0; l < 8; ++l) {
      int e = t + l * 512;
      int r = e >> 6, k = e & 63;
      sI[r * 65 + k] = invUg[kb * 4096 + r * 64 + k];
    }
    __syncthreads();   // covers initial sZ load (first iter) + sI staging + prior updates
    // x_kb = invU @ z_kb : read phase
    float xv[2];
    #pragma unroll
    for (int rr = 0; rr < 2; ++rr) {
      int i = q * 2 + rr;
      float a0 = 0.f, a1 = 0.f;
      #pragma unroll
      for (int k = 0; k < 64; k += 2) {
        a0 = fmaf(sI[i * 65 + k], sZ[(kb * 64 + k) * 17 + o], a0);
        a1 = fmaf(sI[i * 65 + k + 1], sZ[(kb * 64 + k + 1) * 17 + o], a1);
      }
      xv[rr] = a0 + a1;
    }
    __syncthreads();   // all reads of z_kb done before overwrite
    #pragma unroll
    for (int rr = 0; rr < 2; ++rr) {
      int i = q * 2 + rr;
      sZ[(kb * 64 + i) * 17 + o] = xv[rr];
      Gt[(kb * 64 + i) * 128 + c0 + o] = xv[rr];
    }
    __syncthreads();
    if (kb == 0) break;
    // hoist x_kb into registers once (each thread: its own column o) -- STATIC indices only
    float xk[64];
    #pragma unroll
    for (int k = 0; k < 64; ++k) xk[k] = sZ[(kb * 64 + k) * 17 + o];
    // updates: z_i -= U(i,kb) @ x_kb for i < kb, with reg-staged double-buffered U tiles
    float bufA[8], bufB[8];
    #pragma unroll
    for (int l = 0; l < 8; ++l) {
      int e = t + l * 512;
      int r = e >> 6, k = e & 63;
      bufA[l] = M[r * 640 + kb * 64 + k];          // i = 0 tile
    }
    for (int i = 0; i < kb; ++i) {
      #pragma unroll
      for (int l = 0; l < 8; ++l) {
        int e = t + l * 512;
        int r = e >> 6, k = e & 63;
        sU[r * 65 + k] = bufA[l];
      }
      if (i + 1 < kb) {
        #pragma unroll
        for (int l = 0; l < 8; ++l) {
          int e = t + l * 512;
          int r = e >> 6, k = e & 63;
          bufB[l] = M[((i + 1) * 64 + r) * 640 + kb * 64 + k];   // prefetch next tile
        }
      }
      __syncthreads();
      #pragma unroll
      for (int rr = 0; rr < 2; ++rr) {
        int row = q * 2 + rr;
        float acc = sZ[(i * 64 + row) * 17 + o];
        #pragma unroll
        for (int k = 0; k < 64; ++k)
          acc = fmaf(-sU[row * 65 + k], xk[k], acc);
        sZ[(i * 64 + row) * 17 + o] = acc;
      }
      #pragma unroll
      for (int l = 0; l < 8; ++l) bufA[l] = bufB[l];
      __syncthreads();   // compute done reading sU before next iteration overwrites it
    }
  }
}

// ---------------- W1 = G@B1 + D21, W2 = G@B2 + D22, bias = G@Fx ----------------
__global__ void k_wass(const float* __restrict__ Gt, const float* __restrict__ H,
                       const float* __restrict__ B2, const float* __restrict__ D21,
                       const float* __restrict__ D22, const float* __restrict__ Fx,
                       float* __restrict__ W1, float* __restrict__ W2, float* __restrict__ bias) {
  int idx = blockIdx.x * 256 + threadIdx.x;
  if (idx < 16384) {
    int o = idx >> 7, j = idx & 127;
    float s = 0.f;
    for (int a = 0; a < 512; ++a) s = fmaf(Gt[a * 128 + o], H[(640 + a) * 1152 + 512 + j], s);
    W1[idx] = s + D21[idx];
  } else if (idx < 32768) {
    int q = idx - 16384;
    int o = q >> 7, j = q & 127;
    float s = 0.f;
    for (int a = 0; a < 512; ++a) s = fmaf(Gt[a * 128 + o], B2[a * 128 + j], s);
    W2[q] = s + D22[q];
  } else if (idx < 32768 + 128) {
    int o = idx - 32768;
    float s = 0.f;
    for (int a = 0; a < 512; ++a) s = fmaf(Gt[a * 128 + o], Fx[a], s);
    bias[o] = s;
  }
}

// ---------------- baseT[i][b] = xc[i] + (u @ D12^T)[b][i] ----------------
__global__ __launch_bounds__(256) void k_ud(const float* __restrict__ u, const float* __restrict__ D12,
                                            const float* __restrict__ xc, float* __restrict__ baseT) {
  __shared__ float sU[32][65];
  __shared__ float sD[32][65];
  const int t = threadIdx.x;
  const int b0 = blockIdx.x * 64, i0 = blockIdx.y * 64;
  const int tm = t & 15, tn = t >> 4;
  float acc[4][4] = {};
  for (int k0 = 0; k0 < 128; k0 += 32) {
    #pragma unroll
    for (int l = 0; l < 2; ++l) {
      int idx = t + l * 256;
      int row = idx >> 3, k4 = (idx & 7) << 2;
      float4 v = *(const float4*)&u[(b0 + row) * 128 + k0 + k4];
      sU[k4 + 0][row] = v.x; sU[k4 + 1][row] = v.y; sU[k4 + 2][row] = v.z; sU[k4 + 3][row] = v.w;
      float4 d = *(const float4*)&D12[(i0 + row) * 128 + k0 + k4];
      sD[k4 + 0][row] = d.x; sD[k4 + 1][row] = d.y; sD[k4 + 2][row] = d.z; sD[k4 + 3][row] = d.w;
    }
    __syncthreads();
    #pragma unroll
    for (int kk = 0; kk < 32; ++kk) {
      float mm[4], nn[4];
      #pragma unroll
      for (int q = 0; q < 4; ++q) mm[q] = sU[kk][tm * 4 + q];
      #pragma unroll
      for (int q = 0; q < 4; ++q) nn[q] = sD[kk][tn * 4 + q];
      #pragma unroll
      for (int c = 0; c < 4; ++c)
        #pragma unroll
        for (int r = 0; r < 4; ++r)
          acc[c][r] = fmaf(nn[c], mm[r], acc[c][r]);
    }
    __syncthreads();
  }
  #pragma unroll
  for (int c = 0; c < 4; ++c) {
    int i = i0 + tn * 4 + c;
    float xcv = xc[i];
    float4 v = make_float4(acc[c][0] + xcv, acc[c][1] + xcv, acc[c][2] + xcv, acc[c][3] + xcv);
    *(float4*)&baseT[i * BATCH + b0 + tm * 4] = v;
  }
}

// ---------------- scan: w[i] = tanh((base_i + sum_{j<i} D11[i][j] w[j]) / Lam[i]) ----------------
// 4-wave version. Round-11 counters: Occupancy 2.78% (256 waves on 1024 SIMDs), VALUBusy 3.4% --
// the serial-column structure caps the machine at 1/4 SIMDs. The history GEMM (7168 of ~9400
// fmafs/thread) is 16 INDEPENDENT dot products per chunk, so split it across 4 waves covering the
// SAME 64 batch columns: wave w computes hist rows 4w..4w+3 (identical per-chain fmaf order ->
// bitwise-same), passes them via hl[] LDS; wave 0 alone runs the short serial scan (a1 seeded from
// hl -- same value, same combine order) and publishes. 1024 waves total = 1 wave/SIMD chip-wide.
__global__ __launch_bounds__(256, 1) void k_scan(const float* __restrict__ baseT, const float* __restrict__ D11g,
                                                 const float* __restrict__ Lam, float* __restrict__ wT) {
  __shared__ float wl[32 * 260];   // 32 groups x (64 threads x 4 elems + 4 pad)
  __shared__ float hl[16 * 68];    // hist staging: 16 rows x 64 cols (+4 pad)
  const int t = threadIdx.x & 63;  // batch lane (column)
  const int w = threadIdx.x >> 6;  // wave id 0..3
  const int b = blockIdx.x * 64 + t;
  for (int c = 0; c < 8; ++c) {
    const int C = c * 16;
    // wave 0 issues its baseT loads early so HBM latency hides under the hist phase
    float bt[16];
    if (w == 0) {
      #pragma unroll
      for (int l = 0; l < 16; ++l) bt[l] = baseT[(C + l) * BATCH + b];
    }
    // all waves: hist for li = 4w .. 4w+3 (independent chains, order identical to round 11)
    float h0 = 0.f, h1 = 0.f, h2 = 0.f, h3 = 0.f;
    for (int g = 0; g < C / 4; ++g) {
      float4 wv = *(const float4*)&wl[g * 260 + t * 4];
      const float* __restrict__ D0 = D11g + (C + w * 4 + 0) * 128 + g * 4;
      const float* __restrict__ D1 = D11g + (C + w * 4 + 1) * 128 + g * 4;
      const float* __restrict__ D2 = D11g + (C + w * 4 + 2) * 128 + g * 4;
      const float* __restrict__ D3 = D11g + (C + w * 4 + 3) * 128 + g * 4;
      h0 = fmaf(wv.x, D0[0], h0); h0 = fmaf(wv.y, D0[1], h0); h0 = fmaf(wv.z, D0[2], h0); h0 = fmaf(wv.w, D0[3], h0);
      h1 = fmaf(wv.x, D1[0], h1); h1 = fmaf(wv.y, D1[1], h1); h1 = fmaf(wv.z, D1[2], h1); h1 = fmaf(wv.w, D1[3], h1);
      h2 = fmaf(wv.x, D2[0], h2); h2 = fmaf(wv.y, D2[1], h2); h2 = fmaf(wv.z, D2[2], h2); h2 = fmaf(wv.w, D2[3], h2);
      h3 = fmaf(wv.x, D3[0], h3); h3 = fmaf(wv.y, D3[1], h3); h3 = fmaf(wv.z, D3[2], h3); h3 = fmaf(wv.w, D3[3], h3);
    }
    hl[(w * 4 + 0) * 68 + t] = h0;
    hl[(w * 4 + 1) * 68 + t] = h1;
    hl[(w * 4 + 2) * 68 + t] = h2;
    hl[(w * 4 + 3) * 68 + t] = h3;
    __syncthreads();
    if (w == 0) {
      float wc[16];
      #pragma unroll
      for (int li = 0; li < 16; ++li) {
        const int i = C + li;
        const float* __restrict__ Drow = D11g + i * 128;
        float a0 = bt[li], a1 = hl[li * 68 + t], a2 = 0.f, a3 = 0.f;
        #pragma unroll
        for (int lg = 0; lg + 4 <= li; lg += 4) {
          a0 = fmaf(wc[lg + 0], Drow[C + lg + 0], a0);
          a1 = fmaf(wc[lg + 1], Drow[C + lg + 1], a1);
          a2 = fmaf(wc[lg + 2], Drow[C + lg + 2], a2);
          a3 = fmaf(wc[lg + 3], Drow[C + lg + 3], a3);
        }
        #pragma unroll
        for (int lj = li & ~3; lj < li; ++lj) a0 = fmaf(wc[lj], Drow[C + lj], a0);
        float zv = ((a0 + a1) + (a2 + a3)) / Lam[i];
        float az = fabsf(zv);
        float e = __expf(-2.0f * az);
        float th = (1.0f - e) / (1.0f + e);
        wc[li] = copysignf(th, zv);
      }
      #pragma unroll
      for (int gg = 0; gg < 4; ++gg) {
        float4 o = make_float4(wc[gg * 4 + 0], wc[gg * 4 + 1], wc[gg * 4 + 2], wc[gg * 4 + 3]);
        *(float4*)&wl[(C / 4 + gg) * 260 + t * 4] = o;
      }
      #pragma unroll
      for (int li = 0; li < 16; ++li) wT[(C + li) * BATCH + b] = wc[li];
    }
    __syncthreads();   // wl chunk published before next chunk's hist phase reads it
  }
}

// ---------------- y = w@W1^T + u@W2^T + bias ----------------
__global__ __launch_bounds__(256) void k_y(const float* __restrict__ wT, const float* __restrict__ u,
                                           const float* __restrict__ W1, const float* __restrict__ W2,
                                           const float* __restrict__ bias, float* __restrict__ y) {
  __shared__ float sA[32][65];
  __shared__ float sW[32][65];
  const int t = threadIdx.x;
  const int b0 = blockIdx.x * 64, o0 = blockIdx.y * 64;
  const int tn = t & 15, tm = t >> 4;
  float acc[4][4] = {};
  for (int k0 = 0; k0 < 128; k0 += 32) {
    #pragma unroll
    for (int l = 0; l < 2; ++l) {
      int idx = t + l * 256;
      int kk = idx >> 4, c4 = (idx & 15) << 2;
      float4 v = *(const float4*)&wT[(k0 + kk) * BATCH + b0 + c4];
      sA[kk][c4 + 0] = v.x; sA[kk][c4 + 1] = v.y; sA[kk][c4 + 2] = v.z; sA[kk][c4 + 3] = v.w;
      int row = idx >> 3, k4 = (idx & 7) << 2;
      float4 d = *(const float4*)&W1[(o0 + row) * 128 + k0 + k4];
      sW[k4 + 0][row] = d.x; sW[k4 + 1][row] = d.y; sW[k4 + 2][row] = d.z; sW[k4 + 3][row] = d.w;
    }
    __syncthreads();
    #pragma unroll
    for (int kk = 0; kk < 32; ++kk) {
      float mm[4], nn[4];
      #pragma unroll
      for (int q = 0; q < 4; ++q) mm[q] = sA[kk][tm * 4 + q];
      #pragma unroll
      for (int q = 0; q < 4; ++q) nn[q] = sW[kk][tn * 4 + q];
      #pragma unroll
      for (int r = 0; r < 4; ++r)
        #pragma unroll
        for (int c = 0; c < 4; ++c)
          acc[r][c] = fmaf(mm[r], nn[c], acc[r][c]);
    }
    __syncthreads();
  }
  for (int k0 = 0; k0 < 128; k0 += 32) {
    #pragma unroll
    for (int l = 0; l < 2; ++l) {
      int idx = t + l * 256;
      int row = idx >> 3, k4 = (idx & 7) << 2;
      float4 v = *(const float4*)&u[(b0 + row) * 128 + k0 + k4];
      sA[k4 + 0][row] = v.x; sA[k4 + 1][row] = v.y; sA[k4 + 2][row] = v.z; sA[k4 + 3][row] = v.w;
      float4 d = *(const float4*)&W2[(o0 + row) * 128 + k0 + k4];
      sW[k4 + 0][row] = d.x; sW[k4 + 1][row] = d.y; sW[k4 + 2][row] = d.z; sW[k4 + 3][row] = d.w;
    }
    __syncthreads();
    #pragma unroll
    for (int kk = 0; kk < 32; ++kk) {
      float mm[4], nn[4];
      #pragma unroll
      for (int q = 0; q < 4; ++q) mm[q] = sA[kk][tm * 4 + q];
      #pragma unroll
      for (int q = 0; q < 4; ++q) nn[q] = sW[kk][tn * 4 + q];
      #pragma unroll
      for (int r = 0; r < 4; ++r)
        #pragma unroll
        for (int c = 0; c < 4; ++c)
          acc[r][c] = fmaf(mm[r], nn[c], acc[r][c]);
    }
    __syncthreads();
  }
  #pragma unroll
  for (int r = 0; r < 4; ++r) {
    int bb = b0 + tm * 4 + r;
    float4 v = make_float4(acc[r][0] + bias[o0 + tn * 4 + 0],
                           acc[r][1] + bias[o0 + tn * 4 + 1],
                           acc[r][2] + bias[o0 + tn * 4 + 2],
                           acc[r][3] + bias[o0 + tn * 4 + 3]);
    *(float4*)&y[bb * 128 + o0 + tn * 4] = v;
  }
}

extern "C" void kernel_launch(void* const* d_in, const int* in_sizes, int n_in,
                              void* d_out, int out_size, void* d_ws, size_t ws_size,
                              hipStream_t stream) {
  const float* u   = (const float*)d_in[0];
  const float* X   = (const float*)d_in[1];
  const float* Y   = (const float*)d_in[2];
  const float* B2  = (const float*)d_in[3];
  const float* C2  = (const float*)d_in[4];
  const float* D21 = (const float*)d_in[5];
  const float* D22 = (const float*)d_in[6];
  const float* D12 = (const float*)d_in[7];
  const float* x0  = (const float*)d_in[8];

  float* ws = (float*)d_ws;
  float* H     = ws;                    // 1327104
  float* M     = H + 1327104;           // 512*640 = 327680
  float* Gt    = M + 327680;            // 65536
  float* W1    = Gt + 65536;            // 16384
  float* W2    = W1 + 16384;            // 16384
  float* D11   = W2 + 16384;            // 16384
  float* Lam   = D11 + 16384;           // 128
  float* xc    = Lam + 128;             // 128
  float* Fx    = xc + 128;              // 512
  float* bias  = Fx + 512;              // 128
  float* baseT = bias + 128 + 64;       // 128*16384 = 2097152
  float* wT    = baseT;                 // in-place
  // Dfac / invUg alias the dead H11 region (H rows 0..511 cols 0..511 are only read by
  // k_assemble, stream-ordered before the LU). 2 * 8 * 64*64 = 65536 floats = ~57 H-rows.
  float* Dfac  = H;
  float* invUg = H + 32768;
  float* y     = (float*)d_out;

  k_xtx<<<dim3(18, 18), 256, 0, stream>>>(X, H);
  k_assemble<<<388, 256, 0, stream>>>(H, Y, C2, x0, M, D11, Lam, xc, Fx);

  for (int kb = 0; kb < 8; ++kb) {
    k_lu_dp<<<16 - 2 * kb, 64, 0, stream>>>(M, Dfac, kb);
    if (kb < 7)
      k_lu_trailing<<<dim3(9 - kb, 7 - kb), 256, 0, stream>>>(M, kb);
  }

  k_inv<<<8, 64, 0, stream>>>(Dfac, invUg);
  k_bs<<<8, 512, 0, stream>>>(M, invUg, Gt);
  k_wass<<<129, 256, 0, stream>>>(Gt, H, B2, D21, D22, Fx, W1, W2, bias);

  k_ud<<<dim3(256, 2), 256, 0, stream>>>(u, D12, xc, baseT);
  k_scan<<<256, 256, 0, stream>>>(baseT, D11, Lam, wT);
  k_y<<<dim3(256, 2), 256, 0, stream>>>(wT, u, W1, W2, bias, y);
}

// Round 13
// 815.317 us; speedup vs baseline: 1.1657x; 1.0382x over previous
//
#include <hip/hip_runtime.h>
#include <math.h>

#define EPS_C 0.001f
#define BATCH 16384

// ---------------- H = X^T X + eps*I  (1152x1152), symmetric: compute bi<=bj, mirror ----------------
// Stride-68 LDS tiles (272B rows: 16B-aligned float4 slots, rows bank-staggered by 4) so staging
// and fragment access are ds_write_b128/ds_read_b128. Round-12 counters: 8 scalar b32 reads per
// 16 fmafs made this kernel LDS-issue-bound (~37K LDS wave-instrs/CU ~= 89us of the 102us wall).
// float4 cuts LDS instructions 4x at identical fmaf order -> bitwise-identical H.
__global__ __launch_bounds__(256) void k_xtx(const float* __restrict__ X, float* __restrict__ H) {
  __shared__ float smem[2 * 32 * 68];
  const int bi64 = blockIdx.x, bj64 = blockIdx.y;
  if (bi64 > bj64) return;
  float (*sA)[68] = (float(*)[68])smem;
  float (*sB)[68] = (float(*)[68])(smem + 32 * 68);
  const int t = threadIdx.x;
  const int bi = bi64 * 64, bj = bj64 * 64;
  const int tj = t & 15, ti = t >> 4;
  float acc[4][4] = {};
  for (int k0 = 0; k0 < 1152; k0 += 32) {
    #pragma unroll
    for (int l = 0; l < 2; ++l) {
      int idx = t + l * 256;
      int kk = idx >> 4, c4 = (idx & 15) << 2;
      float4 va = *(const float4*)&X[(k0 + kk) * 1152 + bi + c4];
      *(float4*)&sA[kk][c4] = va;
      float4 vb = *(const float4*)&X[(k0 + kk) * 1152 + bj + c4];
      *(float4*)&sB[kk][c4] = vb;
    }
    __syncthreads();
    #pragma unroll
    for (int kk = 0; kk < 32; ++kk) {
      float4 a4 = *(const float4*)&sA[kk][ti * 4];
      float4 b4 = *(const float4*)&sB[kk][tj * 4];
      float am[4], bn[4];
      am[0] = a4.x; am[1] = a4.y; am[2] = a4.z; am[3] = a4.w;
      bn[0] = b4.x; bn[1] = b4.y; bn[2] = b4.z; bn[3] = b4.w;
      #pragma unroll
      for (int r = 0; r < 4; ++r)
        #pragma unroll
        for (int c = 0; c < 4; ++c)
          acc[r][c] = fmaf(am[r], bn[c], acc[r][c]);
    }
    __syncthreads();
  }
  #pragma unroll
  for (int r = 0; r < 4; ++r) {
    int gi = bi + ti * 4 + r;
    float vv[4];
    #pragma unroll
    for (int c = 0; c < 4; ++c) {
      vv[c] = acc[r][c];
      if (gi == bj + tj * 4 + c) vv[c] += EPS_C;
    }
    float4 o = make_float4(vv[0], vv[1], vv[2], vv[3]);
    *(float4*)&H[gi * 1152 + bj + tj * 4] = o;
  }
  if (bi64 < bj64) {
    // transpose through LDS (sA/sB dead after final barrier), coalesced mirror write
    float (*tr)[65] = (float(*)[65])smem;   // 64*65 = 4160 <= 2*32*68 = 4352
    __syncthreads();
    #pragma unroll
    for (int r = 0; r < 4; ++r)
      #pragma unroll
      for (int c = 0; c < 4; ++c)
        tr[tj * 4 + c][ti * 4 + r] = acc[r][c];
    __syncthreads();
    #pragma unroll
    for (int l = 0; l < 4; ++l) {
      int e = t + l * 256;
      int row = e >> 4, c4 = (e & 15) << 2;
      float4 o = make_float4(tr[row][c4], tr[row][c4 + 1], tr[row][c4 + 2], tr[row][c4 + 3]);
      *(float4*)&H[(bj + row) * 1152 + bi + c4] = o;
    }
  }
}

// ---------------- assemble M=[E^T | C2^T], D11, Lam, xc, Fx ----------------
__global__ __launch_bounds__(256) void k_assemble(const float* __restrict__ H, const float* __restrict__ Y,
                           const float* __restrict__ C2, const float* __restrict__ x0,
                           float* __restrict__ M, float* __restrict__ D11,
                           float* __restrict__ Lam, float* __restrict__ xc, float* __restrict__ Fx) {
  const int b = blockIdx.x;
  const int t = threadIdx.x;
  if (b < 256) {
    __shared__ float tA[32][33], tB[32][33], tC[32][33];
    const int R0 = (b & 15) * 32, C0 = (b >> 4) * 32;
    const int c = t & 31, rr = t >> 5;
    #pragma unroll
    for (int p = 0; p < 4; ++p) {
      int row = rr + p * 8;
      tA[row][c] = H[(C0 + row) * 1152 + R0 + c];
      tB[row][c] = H[(640 + C0 + row) * 1152 + 640 + R0 + c];
      tC[row][c] = Y[(C0 + row) * 512 + R0 + c];
    }
    __syncthreads();
    #pragma unroll
    for (int p = 0; p < 4; ++p) {
      int r = rr + p * 8;
      float val = 0.5f * (tA[c][r] + tB[c][r] + tC[c][r] - Y[(R0 + r) * 512 + C0 + c]);
      M[(R0 + r) * 640 + C0 + c] = val;
    }
  } else if (b < 320) {
    int e0 = (b - 256) * 1024;
    #pragma unroll
    for (int l = 0; l < 4; ++l) {
      int e = e0 + l * 256 + t;
      int r = e >> 7, o = e & 127;
      M[r * 640 + 512 + o] = C2[o * 512 + r];
    }
  } else if (b < 384) {
    int e = (b - 320) * 256 + t;
    int i = e >> 7, j = e & 127;
    D11[e] = (j < i) ? -H[(512 + i) * 1152 + 512 + j] : 0.0f;
  } else if (b == 384) {
    if (t < 128) Lam[t] = 0.5f * H[(512 + t) * 1152 + 512 + t];
  } else if (b == 385) {
    if (t < 128) {
      float s = 0.f;
      for (int a = 0; a < 512; ++a) s = fmaf(H[(512 + t) * 1152 + a], x0[a], s);
      xc[t] = -s;
    }
  } else {
    int r = (b - 386) * 256 + t;
    float s = 0.f;
    for (int a = 0; a < 512; ++a) s = fmaf(H[(640 + r) * 1152 + a], x0[a], s);
    Fx[r] = s;
  }
}

// ---------------- fused diag+panels: every block redundantly factors the 64x64 diag in registers
//                  (no inter-block sync); block 0 persists factored diag to Dfac (NOT in-place: race-free) ----------------
__global__ __launch_bounds__(64) void k_lu_dp(float* __restrict__ M, float* __restrict__ Dfac, int kb) {
  __shared__ float sD[64 * 65];
  __shared__ float sRD[64];
  const int t = threadIdx.x;
  const int nU = 9 - kb;
  const int pb = blockIdx.x;
  // issue panel loads early (panel strips are untouched by the diag factor)
  float v[64];
  int c = 0, rr = 0;
  if (pb < nU) {
    c = 64 * (kb + 1) + pb * 64 + t;
    #pragma unroll
    for (int i = 0; i < 64; ++i) v[i] = M[(kb * 64 + i) * 640 + c];
  } else {
    rr = 64 * (kb + 1) + (pb - nU) * 64 + t;
    #pragma unroll
    for (int i = 0; i < 16; ++i) *(float4*)&v[i * 4] = *(const float4*)&M[rr * 640 + kb * 64 + i * 4];
  }
  // redundant in-register LU factor of diag (reads ORIGINAL M diag; M's diag is never overwritten)
  {
    const float* blk = M + kb * 64 * 640 + kb * 64;
    float col[64];
    #pragma unroll
    for (int r = 0; r < 64; ++r) col[r] = blk[r * 640 + t];
    float invp = 1.0f;
    #pragma unroll
    for (int k = 0; k < 64; ++k) {
      float piv = __shfl(col[k], k);
      float inv = 1.0f / piv;
      if (t == k) invp = inv;
      float m = col[k] * inv;
      bool act = t > k;
      #pragma unroll
      for (int r = k + 1; r < 64; ++r) {
        float ckr = __shfl(col[r], k);
        if (act) col[r] -= ckr * m;
      }
    }
    #pragma unroll
    for (int r = 0; r < 64; ++r) {
      if (r > t) col[r] *= invp;
      sD[r * 65 + t] = col[r];
      if (pb == 0) Dfac[kb * 4096 + r * 64 + t] = col[r];
    }
    sRD[t] = invp;  // == 1/sD[t*65+t] bitwise
  }
  __syncthreads();
  if (pb < nU) {
    #pragma unroll
    for (int i = 1; i < 64; ++i) {
      float a0 = v[i], a1 = 0.f;
      #pragma unroll
      for (int j = 0; j < i; j += 2) {
        a0 = fmaf(-sD[i * 65 + j], v[j], a0);
        if (j + 1 < i) a1 = fmaf(-sD[i * 65 + j + 1], v[j + 1], a1);
      }
      v[i] = a0 + a1;
    }
    #pragma unroll
    for (int i = 0; i < 64; ++i) M[(kb * 64 + i) * 640 + c] = v[i];
  } else {
    #pragma unroll
    for (int j = 0; j < 64; ++j) {
      float a0 = v[j], a1 = 0.f;
      #pragma unroll
      for (int i = 0; i < j; i += 2) {
        a0 = fmaf(-v[i], sD[i * 65 + j], a0);
        if (i + 1 < j) a1 = fmaf(-v[i + 1], sD[(i + 1) * 65 + j], a1);
      }
      v[j] = (a0 + a1) * sRD[j];
    }
    #pragma unroll
    for (int i = 0; i < 16; ++i) *(float4*)&M[rr * 640 + kb * 64 + i * 4] = *(float4*)&v[i * 4];
  }
}

// ---------------- trailing update: A22 -= L21 * U12 (cols include augmented) ----------------
__global__ __launch_bounds__(256) void k_lu_trailing(float* __restrict__ M, int kb) {
  __shared__ float sL[32][65];
  __shared__ float sU[32][65];
  const int t = threadIdx.x;
  const int base = 64 * (kb + 1);
  const int r0 = base + blockIdx.y * 64, c0 = base + blockIdx.x * 64;
  const int tj = t & 15, ti = t >> 4;
  float acc[4][4] = {};
  for (int k0 = 0; k0 < 64; k0 += 32) {
    #pragma unroll
    for (int l = 0; l < 2; ++l) {
      int idx = t + l * 256;
      int row = idx >> 3, k4 = (idx & 7) << 2;
      float4 v = *(const float4*)&M[(r0 + row) * 640 + kb * 64 + k0 + k4];
      sL[k4 + 0][row] = v.x; sL[k4 + 1][row] = v.y; sL[k4 + 2][row] = v.z; sL[k4 + 3][row] = v.w;
      int kk = idx >> 4, c4 = (idx & 15) << 2;
      float4 u4 = *(const float4*)&M[(kb * 64 + k0 + kk) * 640 + c0 + c4];
      sU[kk][c4 + 0] = u4.x; sU[kk][c4 + 1] = u4.y; sU[kk][c4 + 2] = u4.z; sU[kk][c4 + 3] = u4.w;
    }
    __syncthreads();
    #pragma unroll
    for (int kk = 0; kk < 32; ++kk) {
      float am[4], bn[4];
      #pragma unroll
      for (int q = 0; q < 4; ++q) am[q] = sL[kk][ti * 4 + q];
      #pragma unroll
      for (int q = 0; q < 4; ++q) bn[q] = sU[kk][tj * 4 + q];
      #pragma unroll
      for (int r = 0; r < 4; ++r)
        #pragma unroll
        for (int c = 0; c < 4; ++c)
          acc[r][c] = fmaf(am[r], bn[c], acc[r][c]);
    }
    __syncthreads();
  }
  #pragma unroll
  for (int r = 0; r < 4; ++r) {
    float4 old = *(float4*)&M[(r0 + ti * 4 + r) * 640 + c0 + tj * 4];
    old.x -= acc[r][0]; old.y -= acc[r][1]; old.z -= acc[r][2]; old.w -= acc[r][3];
    *(float4*)&M[(r0 + ti * 4 + r) * 640 + c0 + tj * 4] = old;
  }
}

// ---------------- invert each factored 64x64 diag block: invU[kb] = U_kk^-1 (8 parallel blocks) ----------------
__global__ __launch_bounds__(64) void k_inv(const float* __restrict__ Dfac, float* __restrict__ invU) {
  __shared__ float sD[64 * 65];
  __shared__ float srs[64];
  const int t = threadIdx.x;
  const int kb = blockIdx.x;
  for (int l = 0; l < 64; ++l) sD[l * 65 + t] = Dfac[kb * 4096 + l * 64 + t];
  __syncthreads();
  srs[t] = 1.0f / sD[t * 65 + t];
  __syncthreads();
  // column t of U^-1 via back-substitution, fully unrolled, registers only
  float v[64];
  #pragma unroll
  for (int i = 0; i < 64; ++i) v[i] = (i == t) ? srs[t] : 0.0f;
  #pragma unroll
  for (int i = 62; i >= 0; --i) {
    float a0 = 0.f, a1 = 0.f;
    #pragma unroll
    for (int j = i + 1; j < 64; j += 2) {
      a0 = fmaf(-sD[i * 65 + j], v[j], a0);
      if (j + 1 < 64) a1 = fmaf(-sD[i * 65 + j + 1], v[j + 1], a1);
    }
    float nv = (a0 + a1) * srs[i];
    v[i] = (i == t) ? v[i] : nv;   // nv==0 naturally for i>t (strictly-upper zeros)
  }
  #pragma unroll
  for (int i = 0; i < 64; ++i) invU[kb * 4096 + i * 64 + t] = v[i];
}

// ---------------- backward solve U * Gt = Z : 8 INDEPENDENT column-slice blocks (16 cols each) ----------------
__global__ __launch_bounds__(512, 2) void k_bs(const float* __restrict__ M, const float* __restrict__ invUg,
                                               float* __restrict__ Gt) {
  __shared__ float sZ[512 * 17];     // 512 rows x 16 cols, stride 17 (bank-spread)
  __shared__ float sU[64 * 65];
  __shared__ float sI[64 * 65];      // padded: (i*65+k)%32 varies with i
  const int t = threadIdx.x;
  const int c0 = blockIdx.x * 16;
  const int o = t & 15, q = t >> 4;  // q in [0,32): row-thread groups
  // load this block's Z slice (augmented columns of M)
  #pragma unroll
  for (int l = 0; l < 16; ++l) {
    int e = t + l * 512;
    int r = e >> 4, oo = e & 15;
    sZ[r * 17 + oo] = M[r * 640 + 512 + c0 + oo];
  }
  for (int kb = 7; kb >= 0; --kb) {
    // stage invU(kb), padded stride
    #pragma unroll
    for (int l = 0; l < 8; ++l) {
      int e = t + l * 512;
      int r = e >> 6, k = e & 63;
      sI[r * 65 + k] = invUg[kb * 4096 + r * 64 + k];
    }
    __syncthreads();   // covers initial sZ load (first iter) + sI staging + prior updates
    // x_kb = invU @ z_kb : read phase
    float xv[2];
    #pragma unroll
    for (int rr = 0; rr < 2; ++rr) {
      int i = q * 2 + rr;
      float a0 = 0.f, a1 = 0.f;
      #pragma unroll
      for (int k = 0; k < 64; k += 2) {
        a0 = fmaf(sI[i * 65 + k], sZ[(kb * 64 + k) * 17 + o], a0);
        a1 = fmaf(sI[i * 65 + k + 1], sZ[(kb * 64 + k + 1) * 17 + o], a1);
      }
      xv[rr] = a0 + a1;
    }
    __syncthreads();   // all reads of z_kb done before overwrite
    #pragma unroll
    for (int rr = 0; rr < 2; ++rr) {
      int i = q * 2 + rr;
      sZ[(kb * 64 + i) * 17 + o] = xv[rr];
      Gt[(kb * 64 + i) * 128 + c0 + o] = xv[rr];
    }
    __syncthreads();
    if (kb == 0) break;
    // hoist x_kb into registers once (each thread: its own column o) -- STATIC indices only
    float xk[64];
    #pragma unroll
    for (int k = 0; k < 64; ++k) xk[k] = sZ[(kb * 64 + k) * 17 + o];
    // updates: z_i -= U(i,kb) @ x_kb for i < kb, with reg-staged double-buffered U tiles
    float bufA[8], bufB[8];
    #pragma unroll
    for (int l = 0; l < 8; ++l) {
      int e = t + l * 512;
      int r = e >> 6, k = e & 63;
      bufA[l] = M[r * 640 + kb * 64 + k];          // i = 0 tile
    }
    for (int i = 0; i < kb; ++i) {
      #pragma unroll
      for (int l = 0; l < 8; ++l) {
        int e = t + l * 512;
        int r = e >> 6, k = e & 63;
        sU[r * 65 + k] = bufA[l];
      }
      if (i + 1 < kb) {
        #pragma unroll
        for (int l = 0; l < 8; ++l) {
          int e = t + l * 512;
          int r = e >> 6, k = e & 63;
          bufB[l] = M[((i + 1) * 64 + r) * 640 + kb * 64 + k];   // prefetch next tile
        }
      }
      __syncthreads();
      #pragma unroll
      for (int rr = 0; rr < 2; ++rr) {
        int row = q * 2 + rr;
        float acc = sZ[(i * 64 + row) * 17 + o];
        #pragma unroll
        for (int k = 0; k < 64; ++k)
          acc = fmaf(-sU[row * 65 + k], xk[k], acc);
        sZ[(i * 64 + row) * 17 + o] = acc;
      }
      #pragma unroll
      for (int l = 0; l < 8; ++l) bufA[l] = bufB[l];
      __syncthreads();   // compute done reading sU before next iteration overwrites it
    }
  }
}

// ---------------- W1 = G@B1 + D21, W2 = G@B2 + D22, bias = G@Fx ----------------
__global__ void k_wass(const float* __restrict__ Gt, const float* __restrict__ H,
                       const float* __restrict__ B2, const float* __restrict__ D21,
                       const float* __restrict__ D22, const float* __restrict__ Fx,
                       float* __restrict__ W1, float* __restrict__ W2, float* __restrict__ bias) {
  int idx = blockIdx.x * 256 + threadIdx.x;
  if (idx < 16384) {
    int o = idx >> 7, j = idx & 127;
    float s = 0.f;
    for (int a = 0; a < 512; ++a) s = fmaf(Gt[a * 128 + o], H[(640 + a) * 1152 + 512 + j], s);
    W1[idx] = s + D21[idx];
  } else if (idx < 32768) {
    int q = idx - 16384;
    int o = q >> 7, j = q & 127;
    float s = 0.f;
    for (int a = 0; a < 512; ++a) s = fmaf(Gt[a * 128 + o], B2[a * 128 + j], s);
    W2[q] = s + D22[q];
  } else if (idx < 32768 + 128) {
    int o = idx - 32768;
    float s = 0.f;
    for (int a = 0; a < 512; ++a) s = fmaf(Gt[a * 128 + o], Fx[a], s);
    bias[o] = s;
  }
}

// ---------------- baseT[i][b] = xc[i] + (u @ D12^T)[b][i] ----------------
__global__ __launch_bounds__(256) void k_ud(const float* __restrict__ u, const float* __restrict__ D12,
                                            const float* __restrict__ xc, float* __restrict__ baseT) {
  __shared__ float sU[32][65];
  __shared__ float sD[32][65];
  const int t = threadIdx.x;
  const int b0 = blockIdx.x * 64, i0 = blockIdx.y * 64;
  const int tm = t & 15, tn = t >> 4;
  float acc[4][4] = {};
  for (int k0 = 0; k0 < 128; k0 += 32) {
    #pragma unroll
    for (int l = 0; l < 2; ++l) {
      int idx = t + l * 256;
      int row = idx >> 3, k4 = (idx & 7) << 2;
      float4 v = *(const float4*)&u[(b0 + row) * 128 + k0 + k4];
      sU[k4 + 0][row] = v.x; sU[k4 + 1][row] = v.y; sU[k4 + 2][row] = v.z; sU[k4 + 3][row] = v.w;
      float4 d = *(const float4*)&D12[(i0 + row) * 128 + k0 + k4];
      sD[k4 + 0][row] = d.x; sD[k4 + 1][row] = d.y; sD[k4 + 2][row] = d.z; sD[k4 + 3][row] = d.w;
    }
    __syncthreads();
    #pragma unroll
    for (int kk = 0; kk < 32; ++kk) {
      float mm[4], nn[4];
      #pragma unroll
      for (int q = 0; q < 4; ++q) mm[q] = sU[kk][tm * 4 + q];
      #pragma unroll
      for (int q = 0; q < 4; ++q) nn[q] = sD[kk][tn * 4 + q];
      #pragma unroll
      for (int c = 0; c < 4; ++c)
        #pragma unroll
        for (int r = 0; r < 4; ++r)
          acc[c][r] = fmaf(nn[c], mm[r], acc[c][r]);
    }
    __syncthreads();
  }
  #pragma unroll
  for (int c = 0; c < 4; ++c) {
    int i = i0 + tn * 4 + c;
    float xcv = xc[i];
    float4 v = make_float4(acc[c][0] + xcv, acc[c][1] + xcv, acc[c][2] + xcv, acc[c][3] + xcv);
    *(float4*)&baseT[i * BATCH + b0 + tm * 4] = v;
  }
}

// ---------------- scan: w[i] = tanh((base_i + sum_{j<i} D11[i][j] w[j]) / Lam[i]) ----------------
// 4-wave version: wave w computes hist rows 4w..4w+3 (independent chains, identical fmaf order),
// passes via hl[] LDS; wave 0 runs the short serial scan and publishes. 1 wave/SIMD chip-wide.
__global__ __launch_bounds__(256, 1) void k_scan(const float* __restrict__ baseT, const float* __restrict__ D11g,
                                                 const float* __restrict__ Lam, float* __restrict__ wT) {
  __shared__ float wl[32 * 260];   // 32 groups x (64 threads x 4 elems + 4 pad)
  __shared__ float hl[16 * 68];    // hist staging: 16 rows x 64 cols (+4 pad)
  const int t = threadIdx.x & 63;  // batch lane (column)
  const int w = threadIdx.x >> 6;  // wave id 0..3
  const int b = blockIdx.x * 64 + t;
  for (int c = 0; c < 8; ++c) {
    const int C = c * 16;
    // wave 0 issues its baseT loads early so HBM latency hides under the hist phase
    float bt[16];
    if (w == 0) {
      #pragma unroll
      for (int l = 0; l < 16; ++l) bt[l] = baseT[(C + l) * BATCH + b];
    }
    // all waves: hist for li = 4w .. 4w+3 (independent chains, order identical to round 11)
    float h0 = 0.f, h1 = 0.f, h2 = 0.f, h3 = 0.f;
    for (int g = 0; g < C / 4; ++g) {
      float4 wv = *(const float4*)&wl[g * 260 + t * 4];
      const float* __restrict__ D0 = D11g + (C + w * 4 + 0) * 128 + g * 4;
      const float* __restrict__ D1 = D11g + (C + w * 4 + 1) * 128 + g * 4;
      const float* __restrict__ D2 = D11g + (C + w * 4 + 2) * 128 + g * 4;
      const float* __restrict__ D3 = D11g + (C + w * 4 + 3) * 128 + g * 4;
      h0 = fmaf(wv.x, D0[0], h0); h0 = fmaf(wv.y, D0[1], h0); h0 = fmaf(wv.z, D0[2], h0); h0 = fmaf(wv.w, D0[3], h0);
      h1 = fmaf(wv.x, D1[0], h1); h1 = fmaf(wv.y, D1[1], h1); h1 = fmaf(wv.z, D1[2], h1); h1 = fmaf(wv.w, D1[3], h1);
      h2 = fmaf(wv.x, D2[0], h2); h2 = fmaf(wv.y, D2[1], h2); h2 = fmaf(wv.z, D2[2], h2); h2 = fmaf(wv.w, D2[3], h2);
      h3 = fmaf(wv.x, D3[0], h3); h3 = fmaf(wv.y, D3[1], h3); h3 = fmaf(wv.z, D3[2], h3); h3 = fmaf(wv.w, D3[3], h3);
    }
    hl[(w * 4 + 0) * 68 + t] = h0;
    hl[(w * 4 + 1) * 68 + t] = h1;
    hl[(w * 4 + 2) * 68 + t] = h2;
    hl[(w * 4 + 3) * 68 + t] = h3;
    __syncthreads();
    if (w == 0) {
      float wc[16];
      #pragma unroll
      for (int li = 0; li < 16; ++li) {
        const int i = C + li;
        const float* __restrict__ Drow = D11g + i * 128;
        float a0 = bt[li], a1 = hl[li * 68 + t], a2 = 0.f, a3 = 0.f;
        #pragma unroll
        for (int lg = 0; lg + 4 <= li; lg += 4) {
          a0 = fmaf(wc[lg + 0], Drow[C + lg + 0], a0);
          a1 = fmaf(wc[lg + 1], Drow[C + lg + 1], a1);
          a2 = fmaf(wc[lg + 2], Drow[C + lg + 2], a2);
          a3 = fmaf(wc[lg + 3], Drow[C + lg + 3], a3);
        }
        #pragma unroll
        for (int lj = li & ~3; lj < li; ++lj) a0 = fmaf(wc[lj], Drow[C + lj], a0);
        float zv = ((a0 + a1) + (a2 + a3)) / Lam[i];
        float az = fabsf(zv);
        float e = __expf(-2.0f * az);
        float th = (1.0f - e) / (1.0f + e);
        wc[li] = copysignf(th, zv);
      }
      #pragma unroll
      for (int gg = 0; gg < 4; ++gg) {
        float4 o = make_float4(wc[gg * 4 + 0], wc[gg * 4 + 1], wc[gg * 4 + 2], wc[gg * 4 + 3]);
        *(float4*)&wl[(C / 4 + gg) * 260 + t * 4] = o;
      }
      #pragma unroll
      for (int li = 0; li < 16; ++li) wT[(C + li) * BATCH + b] = wc[li];
    }
    __syncthreads();   // wl chunk published before next chunk's hist phase reads it
  }
}

// ---------------- y = w@W1^T + u@W2^T + bias ----------------
__global__ __launch_bounds__(256) void k_y(const float* __restrict__ wT, const float* __restrict__ u,
                                           const float* __restrict__ W1, const float* __restrict__ W2,
                                           const float* __restrict__ bias, float* __restrict__ y) {
  __shared__ float sA[32][65];
  __shared__ float sW[32][65];
  const int t = threadIdx.x;
  const int b0 = blockIdx.x * 64, o0 = blockIdx.y * 64;
  const int tn = t & 15, tm = t >> 4;
  float acc[4][4] = {};
  for (int k0 = 0; k0 < 128; k0 += 32) {
    #pragma unroll
    for (int l = 0; l < 2; ++l) {
      int idx = t + l * 256;
      int kk = idx >> 4, c4 = (idx & 15) << 2;
      float4 v = *(const float4*)&wT[(k0 + kk) * BATCH + b0 + c4];
      sA[kk][c4 + 0] = v.x; sA[kk][c4 + 1] = v.y; sA[kk][c4 + 2] = v.z; sA[kk][c4 + 3] = v.w;
      int row = idx >> 3, k4 = (idx & 7) << 2;
      float4 d = *(const float4*)&W1[(o0 + row) * 128 + k0 + k4];
      sW[k4 + 0][row] = d.x; sW[k4 + 1][row] = d.y; sW[k4 + 2][row] = d.z; sW[k4 + 3][row] = d.w;
    }
    __syncthreads();
    #pragma unroll
    for (int kk = 0; kk < 32; ++kk) {
      float mm[4], nn[4];
      #pragma unroll
      for (int q = 0; q < 4; ++q) mm[q] = sA[kk][tm * 4 + q];
      #pragma unroll
      for (int q = 0; q < 4; ++q) nn[q] = sW[kk][tn * 4 + q];
      #pragma unroll
      for (int r = 0; r < 4; ++r)
        #pragma unroll
        for (int c = 0; c < 4; ++c)
          acc[r][c] = fmaf(mm[r], nn[c], acc[r][c]);
    }
    __syncthreads();
  }
  for (int k0 = 0; k0 < 128; k0 += 32) {
    #pragma unroll
    for (int l = 0; l < 2; ++l) {
      int idx = t + l * 256;
      int row = idx >> 3, k4 = (idx & 7) << 2;
      float4 v = *(const float4*)&u[(b0 + row) * 128 + k0 + k4];
      sA[k4 + 0][row] = v.x; sA[k4 + 1][row] = v.y; sA[k4 + 2][row] = v.z; sA[k4 + 3][row] = v.w;
      float4 d = *(const float4*)&W2[(o0 + row) * 128 + k0 + k4];
      sW[k4 + 0][row] = d.x; sW[k4 + 1][row] = d.y; sW[k4 + 2][row] = d.z; sW[k4 + 3][row] = d.w;
    }
    __syncthreads();
    #pragma unroll
    for (int kk = 0; kk < 32; ++kk) {
      float mm[4], nn[4];
      #pragma unroll
      for (int q = 0; q < 4; ++q) mm[q] = sA[kk][tm * 4 + q];
      #pragma unroll
      for (int q = 0; q < 4; ++q) nn[q] = sW[kk][tn * 4 + q];
      #pragma unroll
      for (int r = 0; r < 4; ++r)
        #pragma unroll
        for (int c = 0; c < 4; ++c)
          acc[r][c] = fmaf(mm[r], nn[c], acc[r][c]);
    }
    __syncthreads();
  }
  #pragma unroll
  for (int r = 0; r < 4; ++r) {
    int bb = b0 + tm * 4 + r;
    float4 v = make_float4(acc[r][0] + bias[o0 + tn * 4 + 0],
                           acc[r][1] + bias[o0 + tn * 4 + 1],
                           acc[r][2] + bias[o0 + tn * 4 + 2],
                           acc[r][3] + bias[o0 + tn * 4 + 3]);
    *(float4*)&y[bb * 128 + o0 + tn * 4] = v;
  }
}

extern "C" void kernel_launch(void* const* d_in, const int* in_sizes, int n_in,
                              void* d_out, int out_size, void* d_ws, size_t ws_size,
                              hipStream_t stream) {
  const float* u   = (const float*)d_in[0];
  const float* X   = (const float*)d_in[1];
  const float* Y   = (const float*)d_in[2];
  const float* B2  = (const float*)d_in[3];
  const float* C2  = (const float*)d_in[4];
  const float* D21 = (const float*)d_in[5];
  const float* D22 = (const float*)d_in[6];
  const float* D12 = (const float*)d_in[7];
  const float* x0  = (const float*)d_in[8];

  float* ws = (float*)d_ws;
  float* H     = ws;                    // 1327104
  float* M     = H + 1327104;           // 512*640 = 327680
  float* Gt    = M + 327680;            // 65536
  float* W1    = Gt + 65536;            // 16384
  float* W2    = W1 + 16384;            // 16384
  float* D11   = W2 + 16384;            // 16384
  float* Lam   = D11 + 16384;           // 128
  float* xc    = Lam + 128;             // 128
  float* Fx    = xc + 128;              // 512
  float* bias  = Fx + 512;              // 128
  float* baseT = bias + 128 + 64;       // 128*16384 = 2097152
  float* wT    = baseT;                 // in-place
  // Dfac / invUg alias the dead H11 region (H rows 0..511 cols 0..511 are only read by
  // k_assemble, stream-ordered before the LU). 2 * 8 * 64*64 = 65536 floats = ~57 H-rows.
  float* Dfac  = H;
  float* invUg = H + 32768;
  float* y     = (float*)d_out;

  k_xtx<<<dim3(18, 18), 256, 0, stream>>>(X, H);
  k_assemble<<<388, 256, 0, stream>>>(H, Y, C2, x0, M, D11, Lam, xc, Fx);

  for (int kb = 0; kb < 8; ++kb) {
    k_lu_dp<<<16 - 2 * kb, 64, 0, stream>>>(M, Dfac, kb);
    if (kb < 7)
      k_lu_trailing<<<dim3(9 - kb, 7 - kb), 256, 0, stream>>>(M, kb);
  }

  k_inv<<<8, 64, 0, stream>>>(Dfac, invUg);
  k_bs<<<8, 512, 0, stream>>>(M, invUg, Gt);
  k_wass<<<129, 256, 0, stream>>>(Gt, H, B2, D21, D22, Fx, W1, W2, bias);

  k_ud<<<dim3(256, 2), 256, 0, stream>>>(u, D12, xc, baseT);
  k_scan<<<256, 256, 0, stream>>>(baseT, D11, Lam, wT);
  k_y<<<dim3(256, 2), 256, 0, stream>>>(wT, u, W1, W2, bias, y);
}

// Round 15
// 811.069 us; speedup vs baseline: 1.1718x; 1.0052x over previous
//
#include <hip/hip_runtime.h>
#include <math.h>

#define EPS_C 0.001f
#define BATCH 16384

// ---------------- H = X^T X + eps*I  (1152x1152), symmetric: compute bi<=bj, mirror ----------------
// Stride-68 float4 LDS tiles (round 13: LDS-issue fix, 102->70us). This round: register
// double-buffered staging -- the 4 global float4 loads per K-step were latency-exposed at the top
// of every iteration (1 wave/SIMD, nothing co-resident to hide them; ~40us of the 70us wall was
// stall). Prologue loads tile 0; each iteration writes regs->LDS, issues NEXT tile's loads
// (s_waitcnt lands only at the next LDS write -> latency hides under the 32-step compute), then
// computes. fmaf order untouched -> bitwise-identical H.
__global__ __launch_bounds__(256) void k_xtx(const float* __restrict__ X, float* __restrict__ H) {
  __shared__ float smem[2 * 32 * 68];
  const int bi64 = blockIdx.x, bj64 = blockIdx.y;
  if (bi64 > bj64) return;
  float (*sA)[68] = (float(*)[68])smem;
  float (*sB)[68] = (float(*)[68])(smem + 32 * 68);
  const int t = threadIdx.x;
  const int bi = bi64 * 64, bj = bj64 * 64;
  const int tj = t & 15, ti = t >> 4;
  const int kk0 = t >> 4, c40 = (t & 15) << 2;          // l = 0 staging coords
  const int kk1 = (t + 256) >> 4, c41 = c40;            // l = 1 staging coords
  float4 pa0, pa1, pb0, pb1;
  // prologue: tile k0 = 0
  pa0 = *(const float4*)&X[(kk0) * 1152 + bi + c40];
  pb0 = *(const float4*)&X[(kk0) * 1152 + bj + c40];
  pa1 = *(const float4*)&X[(kk1) * 1152 + bi + c41];
  pb1 = *(const float4*)&X[(kk1) * 1152 + bj + c41];
  float acc[4][4] = {};
  for (int k0 = 0; k0 < 1152; k0 += 32) {
    *(float4*)&sA[kk0][c40] = pa0;
    *(float4*)&sB[kk0][c40] = pb0;
    *(float4*)&sA[kk1][c41] = pa1;
    *(float4*)&sB[kk1][c41] = pb1;
    if (k0 + 32 < 1152) {
      pa0 = *(const float4*)&X[(k0 + 32 + kk0) * 1152 + bi + c40];
      pb0 = *(const float4*)&X[(k0 + 32 + kk0) * 1152 + bj + c40];
      pa1 = *(const float4*)&X[(k0 + 32 + kk1) * 1152 + bi + c41];
      pb1 = *(const float4*)&X[(k0 + 32 + kk1) * 1152 + bj + c41];
    }
    __syncthreads();
    #pragma unroll
    for (int kk = 0; kk < 32; ++kk) {
      float4 a4 = *(const float4*)&sA[kk][ti * 4];
      float4 b4 = *(const float4*)&sB[kk][tj * 4];
      float am[4], bn[4];
      am[0] = a4.x; am[1] = a4.y; am[2] = a4.z; am[3] = a4.w;
      bn[0] = b4.x; bn[1] = b4.y; bn[2] = b4.z; bn[3] = b4.w;
      #pragma unroll
      for (int r = 0; r < 4; ++r)
        #pragma unroll
        for (int c = 0; c < 4; ++c)
          acc[r][c] = fmaf(am[r], bn[c], acc[r][c]);
    }
    __syncthreads();
  }
  #pragma unroll
  for (int r = 0; r < 4; ++r) {
    int gi = bi + ti * 4 + r;
    float vv[4];
    #pragma unroll
    for (int c = 0; c < 4; ++c) {
      vv[c] = acc[r][c];
      if (gi == bj + tj * 4 + c) vv[c] += EPS_C;
    }
    float4 o = make_float4(vv[0], vv[1], vv[2], vv[3]);
    *(float4*)&H[gi * 1152 + bj + tj * 4] = o;
  }
  if (bi64 < bj64) {
    // transpose through LDS (sA/sB dead after final barrier), coalesced mirror write
    float (*tr)[65] = (float(*)[65])smem;   // 64*65 = 4160 <= 2*32*68 = 4352
    __syncthreads();
    #pragma unroll
    for (int r = 0; r < 4; ++r)
      #pragma unroll
      for (int c = 0; c < 4; ++c)
        tr[tj * 4 + c][ti * 4 + r] = acc[r][c];
    __syncthreads();
    #pragma unroll
    for (int l = 0; l < 4; ++l) {
      int e = t + l * 256;
      int row = e >> 4, c4 = (e & 15) << 2;
      float4 o = make_float4(tr[row][c4], tr[row][c4 + 1], tr[row][c4 + 2], tr[row][c4 + 3]);
      *(float4*)&H[(bj + row) * 1152 + bi + c4] = o;
    }
  }
}

// ---------------- assemble M=[E^T | C2^T], D11, Lam, xc, Fx ----------------
__global__ __launch_bounds__(256) void k_assemble(const float* __restrict__ H, const float* __restrict__ Y,
                           const float* __restrict__ C2, const float* __restrict__ x0,
                           float* __restrict__ M, float* __restrict__ D11,
                           float* __restrict__ Lam, float* __restrict__ xc, float* __restrict__ Fx) {
  const int b = blockIdx.x;
  const int t = threadIdx.x;
  if (b < 256) {
    __shared__ float tA[32][33], tB[32][33], tC[32][33];
    const int R0 = (b & 15) * 32, C0 = (b >> 4) * 32;
    const int c = t & 31, rr = t >> 5;
    #pragma unroll
    for (int p = 0; p < 4; ++p) {
      int row = rr + p * 8;
      tA[row][c] = H[(C0 + row) * 1152 + R0 + c];
      tB[row][c] = H[(640 + C0 + row) * 1152 + 640 + R0 + c];
      tC[row][c] = Y[(C0 + row) * 512 + R0 + c];
    }
    __syncthreads();
    #pragma unroll
    for (int p = 0; p < 4; ++p) {
      int r = rr + p * 8;
      float val = 0.5f * (tA[c][r] + tB[c][r] + tC[c][r] - Y[(R0 + r) * 512 + C0 + c]);
      M[(R0 + r) * 640 + C0 + c] = val;
    }
  } else if (b < 320) {
    int e0 = (b - 256) * 1024;
    #pragma unroll
    for (int l = 0; l < 4; ++l) {
      int e = e0 + l * 256 + t;
      int r = e >> 7, o = e & 127;
      M[r * 640 + 512 + o] = C2[o * 512 + r];
    }
  } else if (b < 384) {
    int e = (b - 320) * 256 + t;
    int i = e >> 7, j = e & 127;
    D11[e] = (j < i) ? -H[(512 + i) * 1152 + 512 + j] : 0.0f;
  } else if (b == 384) {
    if (t < 128) Lam[t] = 0.5f * H[(512 + t) * 1152 + 512 + t];
  } else if (b == 385) {
    if (t < 128) {
      float s = 0.f;
      for (int a = 0; a < 512; ++a) s = fmaf(H[(512 + t) * 1152 + a], x0[a], s);
      xc[t] = -s;
    }
  } else {
    int r = (b - 386) * 256 + t;
    float s = 0.f;
    for (int a = 0; a < 512; ++a) s = fmaf(H[(640 + r) * 1152 + a], x0[a], s);
    Fx[r] = s;
  }
}

// ---------------- fused diag+panels: every block redundantly factors the 64x64 diag in registers
//                  (no inter-block sync); block 0 persists factored diag to Dfac (NOT in-place: race-free) ----------------
__global__ __launch_bounds__(64) void k_lu_dp(float* __restrict__ M, float* __restrict__ Dfac, int kb) {
  __shared__ float sD[64 * 65];
  __shared__ float sRD[64];
  const int t = threadIdx.x;
  const int nU = 9 - kb;
  const int pb = blockIdx.x;
  // issue panel loads early (panel strips are untouched by the diag factor)
  float v[64];
  int c = 0, rr = 0;
  if (pb < nU) {
    c = 64 * (kb + 1) + pb * 64 + t;
    #pragma unroll
    for (int i = 0; i < 64; ++i) v[i] = M[(kb * 64 + i) * 640 + c];
  } else {
    rr = 64 * (kb + 1) + (pb - nU) * 64 + t;
    #pragma unroll
    for (int i = 0; i < 16; ++i) *(float4*)&v[i * 4] = *(const float4*)&M[rr * 640 + kb * 64 + i * 4];
  }
  // redundant in-register LU factor of diag (reads ORIGINAL M diag; M's diag is never overwritten)
  {
    const float* blk = M + kb * 64 * 640 + kb * 64;
    float col[64];
    #pragma unroll
    for (int r = 0; r < 64; ++r) col[r] = blk[r * 640 + t];
    float invp = 1.0f;
    #pragma unroll
    for (int k = 0; k < 64; ++k) {
      float piv = __shfl(col[k], k);
      float inv = 1.0f / piv;
      if (t == k) invp = inv;
      float m = col[k] * inv;
      bool act = t > k;
      #pragma unroll
      for (int r = k + 1; r < 64; ++r) {
        float ckr = __shfl(col[r], k);
        if (act) col[r] -= ckr * m;
      }
    }
    #pragma unroll
    for (int r = 0; r < 64; ++r) {
      if (r > t) col[r] *= invp;
      sD[r * 65 + t] = col[r];
      if (pb == 0) Dfac[kb * 4096 + r * 64 + t] = col[r];
    }
    sRD[t] = invp;  // == 1/sD[t*65+t] bitwise
  }
  __syncthreads();
  if (pb < nU) {
    #pragma unroll
    for (int i = 1; i < 64; ++i) {
      float a0 = v[i], a1 = 0.f;
      #pragma unroll
      for (int j = 0; j < i; j += 2) {
        a0 = fmaf(-sD[i * 65 + j], v[j], a0);
        if (j + 1 < i) a1 = fmaf(-sD[i * 65 + j + 1], v[j + 1], a1);
      }
      v[i] = a0 + a1;
    }
    #pragma unroll
    for (int i = 0; i < 64; ++i) M[(kb * 64 + i) * 640 + c] = v[i];
  } else {
    #pragma unroll
    for (int j = 0; j < 64; ++j) {
      float a0 = v[j], a1 = 0.f;
      #pragma unroll
      for (int i = 0; i < j; i += 2) {
        a0 = fmaf(-v[i], sD[i * 65 + j], a0);
        if (i + 1 < j) a1 = fmaf(-v[i + 1], sD[(i + 1) * 65 + j], a1);
      }
      v[j] = (a0 + a1) * sRD[j];
    }
    #pragma unroll
    for (int i = 0; i < 16; ++i) *(float4*)&M[rr * 640 + kb * 64 + i * 4] = *(float4*)&v[i * 4];
  }
}

// ---------------- trailing update: A22 -= L21 * U12 (cols include augmented) ----------------
__global__ __launch_bounds__(256) void k_lu_trailing(float* __restrict__ M, int kb) {
  __shared__ float sL[32][65];
  __shared__ float sU[32][65];
  const int t = threadIdx.x;
  const int base = 64 * (kb + 1);
  const int r0 = base + blockIdx.y * 64, c0 = base + blockIdx.x * 64;
  const int tj = t & 15, ti = t >> 4;
  float acc[4][4] = {};
  for (int k0 = 0; k0 < 64; k0 += 32) {
    #pragma unroll
    for (int l = 0; l < 2; ++l) {
      int idx = t + l * 256;
      int row = idx >> 3, k4 = (idx & 7) << 2;
      float4 v = *(const float4*)&M[(r0 + row) * 640 + kb * 64 + k0 + k4];
      sL[k4 + 0][row] = v.x; sL[k4 + 1][row] = v.y; sL[k4 + 2][row] = v.z; sL[k4 + 3][row] = v.w;
      int kk = idx >> 4, c4 = (idx & 15) << 2;
      float4 u4 = *(const float4*)&M[(kb * 64 + k0 + kk) * 640 + c0 + c4];
      sU[kk][c4 + 0] = u4.x; sU[kk][c4 + 1] = u4.y; sU[kk][c4 + 2] = u4.z; sU[kk][c4 + 3] = u4.w;
    }
    __syncthreads();
    #pragma unroll
    for (int kk = 0; kk < 32; ++kk) {
      float am[4], bn[4];
      #pragma unroll
      for (int q = 0; q < 4; ++q) am[q] = sL[kk][ti * 4 + q];
      #pragma unroll
      for (int q = 0; q < 4; ++q) bn[q] = sU[kk][tj * 4 + q];
      #pragma unroll
      for (int r = 0; r < 4; ++r)
        #pragma unroll
        for (int c = 0; c < 4; ++c)
          acc[r][c] = fmaf(am[r], bn[c], acc[r][c]);
    }
    __syncthreads();
  }
  #pragma unroll
  for (int r = 0; r < 4; ++r) {
    float4 old = *(float4*)&M[(r0 + ti * 4 + r) * 640 + c0 + tj * 4];
    old.x -= acc[r][0]; old.y -= acc[r][1]; old.z -= acc[r][2]; old.w -= acc[r][3];
    *(float4*)&M[(r0 + ti * 4 + r) * 640 + c0 + tj * 4] = old;
  }
}

// ---------------- invert each factored 64x64 diag block: invU[kb] = U_kk^-1 (8 parallel blocks) ----------------
__global__ __launch_bounds__(64) void k_inv(const float* __restrict__ Dfac, float* __restrict__ invU) {
  __shared__ float sD[64 * 65];
  __shared__ float srs[64];
  const int t = threadIdx.x;
  const int kb = blockIdx.x;
  for (int l = 0; l < 64; ++l) sD[l * 65 + t] = Dfac[kb * 4096 + l * 64 + t];
  __syncthreads();
  srs[t] = 1.0f / sD[t * 65 + t];
  __syncthreads();
  // column t of U^-1 via back-substitution, fully unrolled, registers only
  float v[64];
  #pragma unroll
  for (int i = 0; i < 64; ++i) v[i] = (i == t) ? srs[t] : 0.0f;
  #pragma unroll
  for (int i = 62; i >= 0; --i) {
    float a0 = 0.f, a1 = 0.f;
    #pragma unroll
    for (int j = i + 1; j < 64; j += 2) {
      a0 = fmaf(-sD[i * 65 + j], v[j], a0);
      if (j + 1 < 64) a1 = fmaf(-sD[i * 65 + j + 1], v[j + 1], a1);
    }
    float nv = (a0 + a1) * srs[i];
    v[i] = (i == t) ? v[i] : nv;   // nv==0 naturally for i>t (strictly-upper zeros)
  }
  #pragma unroll
  for (int i = 0; i < 64; ++i) invU[kb * 4096 + i * 64 + t] = v[i];
}

// ---------------- backward solve U * Gt = Z : 8 INDEPENDENT column-slice blocks (16 cols each) ----------------
__global__ __launch_bounds__(512, 2) void k_bs(const float* __restrict__ M, const float* __restrict__ invUg,
                                               float* __restrict__ Gt) {
  __shared__ float sZ[512 * 17];     // 512 rows x 16 cols, stride 17 (bank-spread)
  __shared__ float sU[64 * 65];
  __shared__ float sI[64 * 65];      // padded: (i*65+k)%32 varies with i
  const int t = threadIdx.x;
  const int c0 = blockIdx.x * 16;
  const int o = t & 15, q = t >> 4;  // q in [0,32): row-thread groups
  // load this block's Z slice (augmented columns of M)
  #pragma unroll
  for (int l = 0; l < 16; ++l) {
    int e = t + l * 512;
    int r = e >> 4, oo = e & 15;
    sZ[r * 17 + oo] = M[r * 640 + 512 + c0 + oo];
  }
  for (int kb = 7; kb >= 0; --kb) {
    // stage invU(kb), padded stride
    #pragma unroll
    for (int l = 0; l < 8; ++l) {
      int e = t + l * 512;
      int r = e >> 6, k = e & 63;
      sI[r * 65 + k] = invUg[kb * 4096 + r * 64 + k];
    }
    __syncthreads();   // covers initial sZ load (first iter) + sI staging + prior updates
    // x_kb = invU @ z_kb : read phase
    float xv[2];
    #pragma unroll
    for (int rr = 0; rr < 2; ++rr) {
      int i = q * 2 + rr;
      float a0 = 0.f, a1 = 0.f;
      #pragma unroll
      for (int k = 0; k < 64; k += 2) {
        a0 = fmaf(sI[i * 65 + k], sZ[(kb * 64 + k) * 17 + o], a0);
        a1 = fmaf(sI[i * 65 + k + 1], sZ[(kb * 64 + k + 1) * 17 + o], a1);
      }
      xv[rr] = a0 + a1;
    }
    __syncthreads();   // all reads of z_kb done before overwrite
    #pragma unroll
    for (int rr = 0; rr < 2; ++rr) {
      int i = q * 2 + rr;
      sZ[(kb * 64 + i) * 17 + o] = xv[rr];
      Gt[(kb * 64 + i) * 128 + c0 + o] = xv[rr];
    }
    __syncthreads();
    if (kb == 0) break;
    // hoist x_kb into registers once (each thread: its own column o) -- STATIC indices only
    float xk[64];
    #pragma unroll
    for (int k = 0; k < 64; ++k) xk[k] = sZ[(kb * 64 + k) * 17 + o];
    // updates: z_i -= U(i,kb) @ x_kb for i < kb, with reg-staged double-buffered U tiles
    float bufA[8], bufB[8];
    #pragma unroll
    for (int l = 0; l < 8; ++l) {
      int e = t + l * 512;
      int r = e >> 6, k = e & 63;
      bufA[l] = M[r * 640 + kb * 64 + k];          // i = 0 tile
    }
    for (int i = 0; i < kb; ++i) {
      #pragma unroll
      for (int l = 0; l < 8; ++l) {
        int e = t + l * 512;
        int r = e >> 6, k = e & 63;
        sU[r * 65 + k] = bufA[l];
      }
      if (i + 1 < kb) {
        #pragma unroll
        for (int l = 0; l < 8; ++l) {
          int e = t + l * 512;
          int r = e >> 6, k = e & 63;
          bufB[l] = M[((i + 1) * 64 + r) * 640 + kb * 64 + k];   // prefetch next tile
        }
      }
      __syncthreads();
      #pragma unroll
      for (int rr = 0; rr < 2; ++rr) {
        int row = q * 2 + rr;
        float acc = sZ[(i * 64 + row) * 17 + o];
        #pragma unroll
        for (int k = 0; k < 64; ++k)
          acc = fmaf(-sU[row * 65 + k], xk[k], acc);
        sZ[(i * 64 + row) * 17 + o] = acc;
      }
      #pragma unroll
      for (int l = 0; l < 8; ++l) bufA[l] = bufB[l];
      __syncthreads();   // compute done reading sU before next iteration overwrites it
    }
  }
}

// ---------------- W1 = G@B1 + D21, W2 = G@B2 + D22, bias = G@Fx ----------------
__global__ void k_wass(const float* __restrict__ Gt, const float* __restrict__ H,
                       const float* __restrict__ B2, const float* __restrict__ D21,
                       const float* __restrict__ D22, const float* __restrict__ Fx,
                       float* __restrict__ W1, float* __restrict__ W2, float* __restrict__ bias) {
  int idx = blockIdx.x * 256 + threadIdx.x;
  if (idx < 16384) {
    int o = idx >> 7, j = idx & 127;
    float s = 0.f;
    for (int a = 0; a < 512; ++a) s = fmaf(Gt[a * 128 + o], H[(640 + a) * 1152 + 512 + j], s);
    W1[idx] = s + D21[idx];
  } else if (idx < 32768) {
    int q = idx - 16384;
    int o = q >> 7, j = q & 127;
    float s = 0.f;
    for (int a = 0; a < 512; ++a) s = fmaf(Gt[a * 128 + o], B2[a * 128 + j], s);
    W2[q] = s + D22[q];
  } else if (idx < 32768 + 128) {
    int o = idx - 32768;
    float s = 0.f;
    for (int a = 0; a < 512; ++a) s = fmaf(Gt[a * 128 + o], Fx[a], s);
    bias[o] = s;
  }
}

// ---------------- baseT[i][b] = xc[i] + (u @ D12^T)[b][i] ----------------
__global__ __launch_bounds__(256) void k_ud(const float* __restrict__ u, const float* __restrict__ D12,
                                            const float* __restrict__ xc, float* __restrict__ baseT) {
  __shared__ float sU[32][65];
  __shared__ float sD[32][65];
  const int t = threadIdx.x;
  const int b0 = blockIdx.x * 64, i0 = blockIdx.y * 64;
  const int tm = t & 15, tn = t >> 4;
  float acc[4][4] = {};
  for (int k0 = 0; k0 < 128; k0 += 32) {
    #pragma unroll
    for (int l = 0; l < 2; ++l) {
      int idx = t + l * 256;
      int row = idx >> 3, k4 = (idx & 7) << 2;
      float4 v = *(const float4*)&u[(b0 + row) * 128 + k0 + k4];
      sU[k4 + 0][row] = v.x; sU[k4 + 1][row] = v.y; sU[k4 + 2][row] = v.z; sU[k4 + 3][row] = v.w;
      float4 d = *(const float4*)&D12[(i0 + row) * 128 + k0 + k4];
      sD[k4 + 0][row] = d.x; sD[k4 + 1][row] = d.y; sD[k4 + 2][row] = d.z; sD[k4 + 3][row] = d.w;
    }
    __syncthreads();
    #pragma unroll
    for (int kk = 0; kk < 32; ++kk) {
      float mm[4], nn[4];
      #pragma unroll
      for (int q = 0; q < 4; ++q) mm[q] = sU[kk][tm * 4 + q];
      #pragma unroll
      for (int q = 0; q < 4; ++q) nn[q] = sD[kk][tn * 4 + q];
      #pragma unroll
      for (int c = 0; c < 4; ++c)
        #pragma unroll
        for (int r = 0; r < 4; ++r)
          acc[c][r] = fmaf(nn[c], mm[r], acc[c][r]);
    }
    __syncthreads();
  }
  #pragma unroll
  for (int c = 0; c < 4; ++c) {
    int i = i0 + tn * 4 + c;
    float xcv = xc[i];
    float4 v = make_float4(acc[c][0] + xcv, acc[c][1] + xcv, acc[c][2] + xcv, acc[c][3] + xcv);
    *(float4*)&baseT[i * BATCH + b0 + tm * 4] = v;
  }
}

// ---------------- scan: w[i] = tanh((base_i + sum_{j<i} D11[i][j] w[j]) / Lam[i]) ----------------
// 4-wave version: wave w computes hist rows 4w..4w+3 (independent chains, identical fmaf order),
// passes via hl[] LDS; wave 0 runs the short serial scan and publishes. 1 wave/SIMD chip-wide.
__global__ __launch_bounds__(256, 1) void k_scan(const float* __restrict__ baseT, const float* __restrict__ D11g,
                                                 const float* __restrict__ Lam, float* __restrict__ wT) {
  __shared__ float wl[32 * 260];   // 32 groups x (64 threads x 4 elems + 4 pad)
  __shared__ float hl[16 * 68];    // hist staging: 16 rows x 64 cols (+4 pad)
  const int t = threadIdx.x & 63;  // batch lane (column)
  const int w = threadIdx.x >> 6;  // wave id 0..3
  const int b = blockIdx.x * 64 + t;
  for (int c = 0; c < 8; ++c) {
    const int C = c * 16;
    // wave 0 issues its baseT loads early so HBM latency hides under the hist phase
    float bt[16];
    if (w == 0) {
      #pragma unroll
      for (int l = 0; l < 16; ++l) bt[l] = baseT[(C + l) * BATCH + b];
    }
    // all waves: hist for li = 4w .. 4w+3 (independent chains, order identical to round 11)
    float h0 = 0.f, h1 = 0.f, h2 = 0.f, h3 = 0.f;
    for (int g = 0; g < C / 4; ++g) {
      float4 wv = *(const float4*)&wl[g * 260 + t * 4];
      const float* __restrict__ D0 = D11g + (C + w * 4 + 0) * 128 + g * 4;
      const float* __restrict__ D1 = D11g + (C + w * 4 + 1) * 128 + g * 4;
      const float* __restrict__ D2 = D11g + (C + w * 4 + 2) * 128 + g * 4;
      const float* __restrict__ D3 = D11g + (C + w * 4 + 3) * 128 + g * 4;
      h0 = fmaf(wv.x, D0[0], h0); h0 = fmaf(wv.y, D0[1], h0); h0 = fmaf(wv.z, D0[2], h0); h0 = fmaf(wv.w, D0[3], h0);
      h1 = fmaf(wv.x, D1[0], h1); h1 = fmaf(wv.y, D1[1], h1); h1 = fmaf(wv.z, D1[2], h1); h1 = fmaf(wv.w, D1[3], h1);
      h2 = fmaf(wv.x, D2[0], h2); h2 = fmaf(wv.y, D2[1], h2); h2 = fmaf(wv.z, D2[2], h2); h2 = fmaf(wv.w, D2[3], h2);
      h3 = fmaf(wv.x, D3[0], h3); h3 = fmaf(wv.y, D3[1], h3); h3 = fmaf(wv.z, D3[2], h3); h3 = fmaf(wv.w, D3[3], h3);
    }
    hl[(w * 4 + 0) * 68 + t] = h0;
    hl[(w * 4 + 1) * 68 + t] = h1;
    hl[(w * 4 + 2) * 68 + t] = h2;
    hl[(w * 4 + 3) * 68 + t] = h3;
    __syncthreads();
    if (w == 0) {
      float wc[16];
      #pragma unroll
      for (int li = 0; li < 16; ++li) {
        const int i = C + li;
        const float* __restrict__ Drow = D11g + i * 128;
        float a0 = bt[li], a1 = hl[li * 68 + t], a2 = 0.f, a3 = 0.f;
        #pragma unroll
        for (int lg = 0; lg + 4 <= li; lg += 4) {
          a0 = fmaf(wc[lg + 0], Drow[C + lg + 0], a0);
          a1 = fmaf(wc[lg + 1], Drow[C + lg + 1], a1);
          a2 = fmaf(wc[lg + 2], Drow[C + lg + 2], a2);
          a3 = fmaf(wc[lg + 3], Drow[C + lg + 3], a3);
        }
        #pragma unroll
        for (int lj = li & ~3; lj < li; ++lj) a0 = fmaf(wc[lj], Drow[C + lj], a0);
        float zv = ((a0 + a1) + (a2 + a3)) / Lam[i];
        float az = fabsf(zv);
        float e = __expf(-2.0f * az);
        float th = (1.0f - e) / (1.0f + e);
        wc[li] = copysignf(th, zv);
      }
      #pragma unroll
      for (int gg = 0; gg < 4; ++gg) {
        float4 o = make_float4(wc[gg * 4 + 0], wc[gg * 4 + 1], wc[gg * 4 + 2], wc[gg * 4 + 3]);
        *(float4*)&wl[(C / 4 + gg) * 260 + t * 4] = o;
      }
      #pragma unroll
      for (int li = 0; li < 16; ++li) wT[(C + li) * BATCH + b] = wc[li];
    }
    __syncthreads();   // wl chunk published before next chunk's hist phase reads it
  }
}

// ---------------- y = w@W1^T + u@W2^T + bias ----------------
__global__ __launch_bounds__(256) void k_y(const float* __restrict__ wT, const float* __restrict__ u,
                                           const float* __restrict__ W1, const float* __restrict__ W2,
                                           const float* __restrict__ bias, float* __restrict__ y) {
  __shared__ float sA[32][65];
  __shared__ float sW[32][65];
  const int t = threadIdx.x;
  const int b0 = blockIdx.x * 64, o0 = blockIdx.y * 64;
  const int tn = t & 15, tm = t >> 4;
  float acc[4][4] = {};
  for (int k0 = 0; k0 < 128; k0 += 32) {
    #pragma unroll
    for (int l = 0; l < 2; ++l) {
      int idx = t + l * 256;
      int kk = idx >> 4, c4 = (idx & 15) << 2;
      float4 v = *(const float4*)&wT[(k0 + kk) * BATCH + b0 + c4];
      sA[kk][c4 + 0] = v.x; sA[kk][c4 + 1] = v.y; sA[kk][c4 + 2] = v.z; sA[kk][c4 + 3] = v.w;
      int row = idx >> 3, k4 = (idx & 7) << 2;
      float4 d = *(const float4*)&W1[(o0 + row) * 128 + k0 + k4];
      sW[k4 + 0][row] = d.x; sW[k4 + 1][row] = d.y; sW[k4 + 2][row] = d.z; sW[k4 + 3][row] = d.w;
    }
    __syncthreads();
    #pragma unroll
    for (int kk = 0; kk < 32; ++kk) {
      float mm[4], nn[4];
      #pragma unroll
      for (int q = 0; q < 4; ++q) mm[q] = sA[kk][tm * 4 + q];
      #pragma unroll
      for (int q = 0; q < 4; ++q) nn[q] = sW[kk][tn * 4 + q];
      #pragma unroll
      for (int r = 0; r < 4; ++r)
        #pragma unroll
        for (int c = 0; c < 4; ++c)
          acc[r][c] = fmaf(mm[r], nn[c], acc[r][c]);
    }
    __syncthreads();
  }
  for (int k0 = 0; k0 < 128; k0 += 32) {
    #pragma unroll
    for (int l = 0; l < 2; ++l) {
      int idx = t + l * 256;
      int row = idx >> 3, k4 = (idx & 7) << 2;
      float4 v = *(const float4*)&u[(b0 + row) * 128 + k0 + k4];
      sA[k4 + 0][row] = v.x; sA[k4 + 1][row] = v.y; sA[k4 + 2][row] = v.z; sA[k4 + 3][row] = v.w;
      float4 d = *(const float4*)&W2[(o0 + row) * 128 + k0 + k4];
      sW[k4 + 0][row] = d.x; sW[k4 + 1][row] = d.y; sW[k4 + 2][row] = d.z; sW[k4 + 3][row] = d.w;
    }
    __syncthreads();
    #pragma unroll
    for (int kk = 0; kk < 32; ++kk) {
      float mm[4], nn[4];
      #pragma unroll
      for (int q = 0; q < 4; ++q) mm[q] = sA[kk][tm * 4 + q];
      #pragma unroll
      for (int q = 0; q < 4; ++q) nn[q] = sW[kk][tn * 4 + q];
      #pragma unroll
      for (int r = 0; r < 4; ++r)
        #pragma unroll
        for (int c = 0; c < 4; ++c)
          acc[r][c] = fmaf(mm[r], nn[c], acc[r][c]);
    }
    __syncthreads();
  }
  #pragma unroll
  for (int r = 0; r < 4; ++r) {
    int bb = b0 + tm * 4 + r;
    float4 v = make_float4(acc[r][0] + bias[o0 + tn * 4 + 0],
                           acc[r][1] + bias[o0 + tn * 4 + 1],
                           acc[r][2] + bias[o0 + tn * 4 + 2],
                           acc[r][3] + bias[o0 + tn * 4 + 3]);
    *(float4*)&y[bb * 128 + o0 + tn * 4] = v;
  }
}

extern "C" void kernel_launch(void* const* d_in, const int* in_sizes, int n_in,
                              void* d_out, int out_size, void* d_ws, size_t ws_size,
                              hipStream_t stream) {
  const float* u   = (const float*)d_in[0];
  const float* X   = (const float*)d_in[1];
  const float* Y   = (const float*)d_in[2];
  const float* B2  = (const float*)d_in[3];
  const float* C2  = (const float*)d_in[4];
  const float* D21 = (const float*)d_in[5];
  const float* D22 = (const float*)d_in[6];
  const float* D12 = (const float*)d_in[7];
  const float* x0  = (const float*)d_in[8];

  float* ws = (float*)d_ws;
  float* H     = ws;                    // 1327104
  float* M     = H + 1327104;           // 512*640 = 327680
  float* Gt    = M + 327680;            // 65536
  float* W1    = Gt + 65536;            // 16384
  float* W2    = W1 + 16384;            // 16384
  float* D11   = W2 + 16384;            // 16384
  float* Lam   = D11 + 16384;           // 128
  float* xc    = Lam + 128;             // 128
  float* Fx    = xc + 128;              // 512
  float* bias  = Fx + 512;              // 128
  float* baseT = bias + 128 + 64;       // 128*16384 = 2097152
  float* wT    = baseT;                 // in-place
  // Dfac / invUg alias the dead H11 region (H rows 0..511 cols 0..511 are only read by
  // k_assemble, stream-ordered before the LU). 2 * 8 * 64*64 = 65536 floats = ~57 H-rows.
  float* Dfac  = H;
  float* invUg = H + 32768;
  float* y     = (float*)d_out;

  k_xtx<<<dim3(18, 18), 256, 0, stream>>>(X, H);
  k_assemble<<<388, 256, 0, stream>>>(H, Y, C2, x0, M, D11, Lam, xc, Fx);

  for (int kb = 0; kb < 8; ++kb) {
    k_lu_dp<<<16 - 2 * kb, 64, 0, stream>>>(M, Dfac, kb);
    if (kb < 7)
      k_lu_trailing<<<dim3(9 - kb, 7 - kb), 256, 0, stream>>>(M, kb);
  }

  k_inv<<<8, 64, 0, stream>>>(Dfac, invUg);
  k_bs<<<8, 512, 0, stream>>>(M, invUg, Gt);
  k_wass<<<129, 256, 0, stream>>>(Gt, H, B2, D21, D22, Fx, W1, W2, bias);

  k_ud<<<dim3(256, 2), 256, 0, stream>>>(u, D12, xc, baseT);
  k_scan<<<256, 256, 0, stream>>>(baseT, D11, Lam, wT);
  k_y<<<dim3(256, 2), 256, 0, stream>>>(wT, u, W1, W2, bias, y);
}